// Round 6
// baseline (463.668 us; speedup 1.0000x reference)
//
#include <hip/hip_runtime.h>

// ---------------------------------------------------------------------------
// Fused MHA block on gfx950, fp16 MFMA pipeline.
//   qkv GEMM (16384x2304x768, A=fp32 fused-converted) -> per-head flash
//   attention (192 x 1024x1024x64) -> proj GEMM (16384x768x768)
// GEMMs: 128x128 tiles, 4 waves, v_mfma_f32_16x16x32_f16, (256,3).
//   r5 PMC model: 94% of LDS-BW ceiling (144 KB/CU/iter vs 128 B/cyc).
//   -> A-operand LDS-BYPASS: each wave loads its own A fragments
//      global->regs (next-iter register prefetch); A-reuse (2x in-block,
//      3 co-resident same-m0 blocks) served by L1/L2, not LDS.
//   B-operand: global_load_lds dbuf + r2-verified st-swizzle
//      (source seg ^=2 iff (lane>>5)&1 ; read col quad^=2 iff (l15>>3)&1).
//   LDS traffic halves -> MFMA pipe becomes binding.
// Attention: v_mfma_f32_32x32x16_f16 transposed (S^T = K Q^T, O^T = V^T P^T),
//   P in registers (r1-measured-best; T13/T5 nulled in r4).
// ---------------------------------------------------------------------------

typedef _Float16 half8 __attribute__((ext_vector_type(8)));
typedef _Float16 half4 __attribute__((ext_vector_type(4)));
typedef __fp16   fp16x2 __attribute__((ext_vector_type(2)));
typedef float    f32x4  __attribute__((ext_vector_type(4)));
typedef float    f32x16 __attribute__((ext_vector_type(16)));
typedef unsigned int u32x4 __attribute__((ext_vector_type(4)));

#define DI __device__ __forceinline__

constexpr int   BATCH  = 16;
constexpr int   SEQ    = 1024;
constexpr int   DM     = 768;
constexpr int   NH     = 12;
constexpr int   HD     = 64;
constexpr float SCALE  = 0.125f;          // 1/sqrt(64), folded into Q epilogue
constexpr float LOG2E  = 1.4426950408889634f;

DI void copy16(_Float16* dst, const _Float16* src) {
  *(u32x4*)dst = *(const u32x4*)src;
}

DI int pack_rtz(float a, float b) {
  union { fp16x2 h; int i; } u;
  u.h = __builtin_amdgcn_cvt_pkrtz(a, b);
  return u.i;
}

// async global->LDS, 16 B per lane; lds base must be wave-uniform,
// HW writes lane l at lds + l*16.
DI void gld16(const _Float16* g, _Float16* l) {
  __builtin_amdgcn_global_load_lds(
      (const __attribute__((address_space(1))) void*)g,
      (__attribute__((address_space(3))) void*)l, 16, 0, 0);
}

// ---------------------------------------------------------------------------
// converts (weights only; x conversion is fused into gemm_qkv)
// ---------------------------------------------------------------------------
// both weight transposes in one launch: wt[n*K+k] = w[k*N+n]
__global__ void cvt_wt2_kernel(const float* __restrict__ wq,
                               _Float16* __restrict__ wqT,
                               const float* __restrict__ wp,
                               _Float16* __restrict__ wpT) {
  __shared__ float tile[32][33];
  const int by = blockIdx.y;
  const float* w; _Float16* wt; int N, nb;
  if (by < 72) { w = wq; wt = wqT; N = 2304; nb = by * 32; }
  else         { w = wp; wt = wpT; N = 768;  nb = (by - 72) * 32; }
  const int K = 768;
  int kb = blockIdx.x * 32;
  int tx = threadIdx.x & 31, ty = threadIdx.x >> 5;   // ty 0..7
#pragma unroll
  for (int i = 0; i < 32; i += 8)
    tile[ty + i][tx] = w[(size_t)(kb + ty + i) * N + nb + tx];
  __syncthreads();
#pragma unroll
  for (int i = 0; i < 32; i += 8)
    wt[(size_t)(nb + ty + i) * K + kb + tx] = (_Float16)tile[tx][ty + i];
}

// ---------------------------------------------------------------------------
// GEMM1: qkv = x[16384x768 fp32] @ wqkvT^T + bias, scatter epilogue into
//   Q[bh][n][d] (prescaled by 0.125), K[bh][n][d], VT[bh][d][n]  (fp16)
// A: global fp32 -> reg prefetch -> RTN cvt -> MFMA frags (no LDS).
// B: global_load_lds dbuf, st-swizzled.
// ---------------------------------------------------------------------------
__launch_bounds__(256, 3)
__global__ void gemm_qkv_kernel(const float* __restrict__ X,
                                const _Float16* __restrict__ Bt,
                                const float* __restrict__ bias,
                                _Float16* __restrict__ Qo,
                                _Float16* __restrict__ Ko,
                                _Float16* __restrict__ VTo) {
  // B dbuf = 2 x 4096 halves; epilogue Cs alias needs 64*136 = 8704 halves
  __shared__ _Float16 sh[8704];
  _Float16* Cs = sh;
  const int tid  = threadIdx.x;
  // XCD swizzle: all 18 column tiles of one m0 land on one XCD (lin&7)
  const int lin  = blockIdx.x;
  const int xcd  = lin & 7, j = lin >> 3;
  const int ct   = j % 18;             // 0..17 col tiles
  const int m0   = ((j / 18) * 8 + xcd) * 128;
  const int n0   = ct * 128;
  const int w    = tid >> 6, lane = tid & 63;
  const int quad = lane >> 4, l15 = lane & 15;
  const int wr   = w >> 1, wc = w & 1;

  f32x4 acc[4][4] = {};

  // ---- B staging (gld_lds): granule g = w*128 + c*64 + lane,
  //      dest row r = w*32 + c*16 + (lane>>2); (r>>3)&1 = (lane>>5)&1.
  //      Source seg pre-swizzled so swizzled ds_read returns linear data.
  const int r0  = (w * 128 + lane) >> 2;
  const int s0x = ((lane & 3) ^ (2 * ((lane >> 5) & 1)));
  const _Float16* gbB = Bt + (size_t)(n0 + r0) * 768 + s0x * 8;
  const int ldst = w * 1024;           // dest halves, call 0 (call 1: +512)

  // ---- A direct: frag rows m0 + wr*64 + mi*16 + l15, fp32 cols quad*8..+7
  const float* gA = X + (size_t)(m0 + wr * 64 + l15) * 768 + quad * 8;

  float4 pa0[4], pa1[4];               // next-iter A fp32 (register prefetch)
#pragma unroll
  for (int mi = 0; mi < 4; mi++) {     // prologue: A tile 0
    pa0[mi] = *(const float4*)(gA + mi * 12288);
    pa1[mi] = *(const float4*)(gA + mi * 12288 + 4);
  }
  gld16(gbB,            sh + ldst);    // prologue: B tile 0 -> buf 0
  gld16(gbB + 16 * 768, sh + ldst + 512);

  const int qa = (quad ^ (2 * ((l15 >> 3) & 1))) * 8;   // swizzled read col

  for (int kt = 0; kt < 24; ++kt) {
    __syncthreads();                   // B tile kt landed; A loads completed

    half8 af[4];
#pragma unroll
    for (int mi = 0; mi < 4; mi++) {   // cvt current A to fp16 frags
      half8 h;
      h[0] = (_Float16)pa0[mi].x; h[1] = (_Float16)pa0[mi].y;
      h[2] = (_Float16)pa0[mi].z; h[3] = (_Float16)pa0[mi].w;
      h[4] = (_Float16)pa1[mi].x; h[5] = (_Float16)pa1[mi].y;
      h[6] = (_Float16)pa1[mi].z; h[7] = (_Float16)pa1[mi].w;
      af[mi] = h;
    }

    if (kt < 23) {                     // prefetch next tile (A regs, B lds)
      const int k0 = (kt + 1) * 32;
#pragma unroll
      for (int mi = 0; mi < 4; mi++) {
        pa0[mi] = *(const float4*)(gA + k0 + mi * 12288);
        pa1[mi] = *(const float4*)(gA + k0 + mi * 12288 + 4);
      }
      _Float16* Bsn = sh + ((kt + 1) & 1) * 4096;
      gld16(gbB + k0,            Bsn + ldst);
      gld16(gbB + k0 + 16 * 768, Bsn + ldst + 512);
    }

    const _Float16* Bs = sh + (kt & 1) * 4096;
    half8 bf[4];
#pragma unroll
    for (int ni = 0; ni < 4; ni++)
      bf[ni] = *(const half8*)&Bs[(wc * 64 + ni * 16 + l15) * 32 + qa];

#pragma unroll
    for (int mi = 0; mi < 4; mi++)
#pragma unroll
      for (int ni = 0; ni < 4; ni++)
        acc[mi][ni] = __builtin_amdgcn_mfma_f32_16x16x32_f16(
            af[mi], bf[ni], acc[mi][ni], 0, 0, 0);
  }
  __syncthreads();                     // staging done; LDS free for Cs

  const float oscale = (ct < 6) ? SCALE : 1.0f;
  float bcol[4];
#pragma unroll
  for (int ni = 0; ni < 4; ni++)
    bcol[ni] = bias[n0 + wc * 64 + ni * 16 + l15];

  const int b     = m0 >> 10;
  const int nrow0 = m0 & 1023;
  const int sec   = ct / 6;            // 0=Q 1=K 2=V
  const int h0    = (ct % 6) * 2;

  // two passes of 64 rows each through Cs
#pragma unroll
  for (int p = 0; p < 2; ++p) {
    if (p) __syncthreads();            // pass-0 reads done before overwrite
    if (wr == p) {
#pragma unroll
      for (int mi = 0; mi < 4; mi++)
#pragma unroll
        for (int ni = 0; ni < 4; ni++) {
          int col = wc * 64 + ni * 16 + l15;
          int row = mi * 16 + quad * 4;
#pragma unroll
          for (int r = 0; r < 4; r++)
            Cs[(row + r) * 136 + col] =
                (_Float16)((acc[mi][ni][r] + bcol[ni]) * oscale);
        }
    }
    __syncthreads();

    if (sec < 2) {
      _Float16* dst = (sec == 0) ? Qo : Ko;
      int row = tid >> 2, seg = tid & 3;
      int hl = seg >> 1, off32 = (seg & 1) * 32;
      _Float16* g = dst +
          ((size_t)((b * NH + h0 + hl) * SEQ + nrow0 + p * 64 + row)) * HD + off32;
      const _Float16* s = &Cs[row * 136 + hl * 64 + off32];
      copy16(g, s);
      copy16(g + 8, s + 8);
      copy16(g + 16, s + 16);
      copy16(g + 24, s + 24);
    } else {
      int c = tid & 127, half = tid >> 7;   // col, row half (32 rows each)
      int hl = c >> 6, d = c & 63;
      _Float16 tmp[32];
#pragma unroll
      for (int jj = 0; jj < 32; jj++) tmp[jj] = Cs[(half * 32 + jj) * 136 + c];
      _Float16* g = VTo + ((size_t)((b * NH + h0 + hl) * HD + d)) * SEQ
                        + nrow0 + p * 64 + half * 32;
#pragma unroll
      for (int jj = 0; jj < 4; jj++)
        copy16(g + jj * 8, (const _Float16*)&tmp[jj * 8]);
    }
  }
}

// ---------------------------------------------------------------------------
// Flash attention, transposed: one wg = (bh, 256-q tile), 4 waves x 64 q.
// S^T = K Q^T (32x32x16 MFMA), P^T kept in registers via half-swap shuffles,
// O^T = V^T P^T.  K-tile 64, double-buffered LDS staging.
// ---------------------------------------------------------------------------
__launch_bounds__(256, 2)
__global__ void attn_kernel(const _Float16* __restrict__ Q,
                            const _Float16* __restrict__ K,
                            const _Float16* __restrict__ VT,
                            _Float16* __restrict__ Oh) {
  __shared__ _Float16 smem[2][2][64 * 72];   // [buf][K/V][64 rows][72]
  _Float16* OLds = &smem[0][0][0];           // aliased epilogue staging (36864B)

  const int tid = threadIdx.x;
  const int i   = blockIdx.x;
  const int bh  = (i & 7) * 24 + ((i >> 3) >> 2);   // XCD swizzle: 4 q-blocks
  const int q0  = ((i >> 3) & 3) * 256;             //  of one bh share an XCD
  const int b   = bh / NH, hh = bh - b * NH;
  const int w   = tid >> 6, lane = tid & 63;
  const int l31 = lane & 31, h = lane >> 5;

  const _Float16* Qg = Q  + (size_t)bh * SEQ * HD;
  const _Float16* Kg = K  + (size_t)bh * SEQ * HD;
  const _Float16* Vg = VT + (size_t)bh * HD * SEQ;

  // persistent Q B-frags: qb[N][s] ; B[k=d][n=q] read from Q[q][d] row-major
  half8 qb[2][4];
#pragma unroll
  for (int N = 0; N < 2; N++) {
    const _Float16* qrow = Qg + (size_t)(q0 + w * 64 + N * 32 + l31) * HD + h * 8;
#pragma unroll
    for (int s = 0; s < 4; s++)
      qb[N][s] = *(const half8*)(qrow + s * 16);
  }

  // staging: threads 0-127 stage K tile, 128-255 stage V^T tile (64B each)
  const int  sr  = (tid & 127) >> 1;
  const int  sp  = tid & 1;
  const bool isK = tid < 128;
  const _Float16* sg = isK ? (Kg + sr * HD + sp * 32)
                           : (Vg + (size_t)sr * SEQ + sp * 32);
  const int sstep = isK ? 64 * HD : 64;
  const int soff  = (isK ? 0 : 64 * 72) + sr * 72 + sp * 32;

  u32x4 pf[4];
#pragma unroll
  for (int c = 0; c < 4; c++) pf[c] = *(const u32x4*)(sg + c * 8);
#pragma unroll
  for (int c = 0; c < 4; c++) *(u32x4*)(&smem[0][0][0] + soff + c * 8) = pf[c];

  f32x16 of[2][2];
#pragma unroll
  for (int D = 0; D < 2; D++)
#pragma unroll
    for (int N = 0; N < 2; N++)
#pragma unroll
      for (int r = 0; r < 16; r++) of[D][N][r] = 0.f;
  float m_[2] = {-1e30f, -1e30f}, l_[2] = {0.f, 0.f};

  for (int kt = 0; kt < 16; ++kt) {
    if (kt < 15) {
      const _Float16* nsg = sg + (kt + 1) * sstep;
#pragma unroll
      for (int c = 0; c < 4; c++) pf[c] = *(const u32x4*)(nsg + c * 8);
    }
    __syncthreads();
    const _Float16* Ks = &smem[kt & 1][0][0];
    const _Float16* Vs = &smem[kt & 1][1][0];

    // S^T = K Q^T : 2 m-frags (64 keys) x 2 n-frags (64 q)
    f32x16 sf[2][2];
#pragma unroll
    for (int M = 0; M < 2; M++)
#pragma unroll
      for (int N = 0; N < 2; N++)
#pragma unroll
        for (int r = 0; r < 16; r++) sf[M][N][r] = 0.f;
#pragma unroll
    for (int s = 0; s < 4; s++) {
      half8 ka0 = *(const half8*)&Ks[l31 * 72 + s * 16 + h * 8];
      half8 ka1 = *(const half8*)&Ks[(32 + l31) * 72 + s * 16 + h * 8];
#pragma unroll
      for (int N = 0; N < 2; N++) {
        sf[0][N] = __builtin_amdgcn_mfma_f32_32x32x16_f16(ka0, qb[N][s], sf[0][N], 0, 0, 0);
        sf[1][N] = __builtin_amdgcn_mfma_f32_32x32x16_f16(ka1, qb[N][s], sf[1][N], 0, 0, 0);
      }
    }

    // online softmax; stats are per q = per lane (col of S^T)
    float alpha[2], c1[2], tsum[2];
#pragma unroll
    for (int N = 0; N < 2; N++) {
      float tmax = -1e30f;
#pragma unroll
      for (int r = 0; r < 16; r++)
        tmax = fmaxf(tmax, fmaxf(sf[0][N][r], sf[1][N][r]));
      tmax = fmaxf(tmax, __shfl_xor(tmax, 32, 64));
      float mnew = fmaxf(m_[N], tmax);
      alpha[N] = __builtin_amdgcn_exp2f((m_[N] - mnew) * LOG2E);
      m_[N] = mnew;
      c1[N] = mnew * LOG2E;
      tsum[N] = 0.f;
    }

    // exp -> P^T, pack fp16 pairs into dwords (kept in registers)
    int pdw[2][2][8];
#pragma unroll
    for (int M = 0; M < 2; M++)
#pragma unroll
      for (int N = 0; N < 2; N++) {
#pragma unroll
        for (int r = 0; r < 16; r++) {
          float p = __builtin_amdgcn_exp2f(sf[M][N][r] * LOG2E - c1[N]);
          sf[M][N][r] = p;
          tsum[N] += p;
        }
#pragma unroll
        for (int u = 0; u < 8; u++)
          pdw[M][N][u] = pack_rtz(sf[M][N][2 * u], sf[M][N][2 * u + 1]);
      }
#pragma unroll
    for (int N = 0; N < 2; N++) {
      tsum[N] += __shfl_xor(tsum[N], 32, 64);
      l_[N] = l_[N] * alpha[N] + tsum[N];
    }
#pragma unroll
    for (int D = 0; D < 2; D++)
#pragma unroll
      for (int N = 0; N < 2; N++)
#pragma unroll
        for (int r = 0; r < 16; r++) of[D][N][r] *= alpha[N];

    // O^T += V^T P^T ; P^T B-frags assembled from pdw via lane^32 half-swap
#pragma unroll
    for (int t = 0; t < 4; ++t) {
      const int M = t >> 1, s2 = (t & 1) * 4;
      half8 va0 = *(const half8*)&Vs[l31 * 72 + t * 16 + h * 8];
      half8 va1 = *(const half8*)&Vs[(32 + l31) * 72 + t * 16 + h * 8];
#pragma unroll
      for (int N = 0; N < 2; N++) {
        int a0 = pdw[M][N][s2 + 0], a1 = pdw[M][N][s2 + 1];
        int a2 = pdw[M][N][s2 + 2], a3 = pdw[M][N][s2 + 3];
        int e0 = h ? a0 : a2, e1 = h ? a1 : a3;
        int r0 = __shfl_xor(e0, 32, 64), r1 = __shfl_xor(e1, 32, 64);
        union { u32x4 u; half8 hv; } bb;
        bb.u[0] = h ? r0 : a0; bb.u[1] = h ? r1 : a1;
        bb.u[2] = h ? a2 : r0; bb.u[3] = h ? a3 : r1;
        of[0][N] = __builtin_amdgcn_mfma_f32_32x32x16_f16(va0, bb.hv, of[0][N], 0, 0, 0);
        of[1][N] = __builtin_amdgcn_mfma_f32_32x32x16_f16(va1, bb.hv, of[1][N], 0, 0, 0);
      }
    }

    if (kt < 15) {
      _Float16* dst = &smem[(kt + 1) & 1][0][0] + soff;
#pragma unroll
      for (int c = 0; c < 4; c++) *(u32x4*)(dst + c * 8) = pf[c];
    }
  }

  // epilogue: normalize, transpose O^T -> O through LDS, coalesced store
  __syncthreads();                       // all waves done with staging buffers
  float inv[2] = {1.0f / l_[0], 1.0f / l_[1]};
  int* OW = (int*)OLds;
#pragma unroll
  for (int N = 0; N < 2; N++) {
    const int q_local = w * 64 + N * 32 + l31;
#pragma unroll
    for (int D = 0; D < 2; D++)
#pragma unroll
      for (int u = 0; u < 8; u++) {
        int v = pack_rtz(of[D][N][2 * u] * inv[N], of[D][N][2 * u + 1] * inv[N]);
        int dwi = 16 * D + 4 * (u >> 1) + (u & 1) + 2 * h;
        OW[q_local * 36 + dwi] = v;
      }
  }
  __syncthreads();
#pragma unroll
  for (int p = 0; p < 8; p++) {
    int q = p * 32 + (tid >> 3), c = tid & 7;
    *(u32x4*)(Oh + (size_t)(b * SEQ + q0 + q) * DM + hh * HD + c * 8) =
        *(const u32x4*)&OLds[q * 72 + c * 8];
  }
}

// ---------------------------------------------------------------------------
// GEMM2: out = Oh[16384x768] @ wprojT^T + bias  (fp32 direct stores)
// A: global fp16 -> reg prefetch -> MFMA frags (no LDS). B: gld_lds swizzled.
// ---------------------------------------------------------------------------
__launch_bounds__(256, 3)
__global__ void gemm_proj_kernel(const _Float16* __restrict__ A,
                                 const _Float16* __restrict__ Bt,
                                 const float* __restrict__ bias,
                                 float* __restrict__ out) {
  __shared__ _Float16 sh[8192];      // B dbuf only: 2 x 4096 halves
  const int tid  = threadIdx.x;
  // XCD swizzle: all 6 column tiles of one m0 on one XCD
  const int lin  = blockIdx.x;
  const int xcd  = lin & 7, j = lin >> 3;
  const int ct   = j % 6;
  const int m0   = ((j / 6) * 8 + xcd) * 128;
  const int n0   = ct * 128;
  const int w    = tid >> 6, lane = tid & 63;
  const int quad = lane >> 4, l15 = lane & 15;
  const int wr   = w >> 1, wc = w & 1;

  f32x4 acc[4][4] = {};

  const int r0  = (w * 128 + lane) >> 2;
  const int s0x = ((lane & 3) ^ (2 * ((lane >> 5) & 1)));
  const _Float16* gbB = Bt + (size_t)(n0 + r0) * 768 + s0x * 8;
  const int ldst = w * 1024;

  const _Float16* gA = A + (size_t)(m0 + wr * 64 + l15) * 768 + quad * 8;

  half8 pa[4];
#pragma unroll
  for (int mi = 0; mi < 4; mi++)
    pa[mi] = *(const half8*)(gA + mi * 12288);
  gld16(gbB,            sh + ldst);
  gld16(gbB + 16 * 768, sh + ldst + 512);

  const int qa = (quad ^ (2 * ((l15 >> 3) & 1))) * 8;

  for (int kt = 0; kt < 24; ++kt) {
    __syncthreads();

    half8 af[4];
#pragma unroll
    for (int mi = 0; mi < 4; mi++) af[mi] = pa[mi];

    if (kt < 23) {
      const int k0 = (kt + 1) * 32;
#pragma unroll
      for (int mi = 0; mi < 4; mi++)
        pa[mi] = *(const half8*)(gA + k0 + mi * 12288);
      _Float16* Bsn = sh + ((kt + 1) & 1) * 4096;
      gld16(gbB + k0,            Bsn + ldst);
      gld16(gbB + k0 + 16 * 768, Bsn + ldst + 512);
    }

    const _Float16* Bs = sh + (kt & 1) * 4096;
    half8 bf[4];
#pragma unroll
    for (int ni = 0; ni < 4; ni++)
      bf[ni] = *(const half8*)&Bs[(wc * 64 + ni * 16 + l15) * 32 + qa];

#pragma unroll
    for (int mi = 0; mi < 4; mi++)
#pragma unroll
      for (int ni = 0; ni < 4; ni++)
        acc[mi][ni] = __builtin_amdgcn_mfma_f32_16x16x32_f16(
            af[mi], bf[ni], acc[mi][ni], 0, 0, 0);
  }

  float bcol[4];
#pragma unroll
  for (int ni = 0; ni < 4; ni++)
    bcol[ni] = bias[n0 + wc * 64 + ni * 16 + l15];
#pragma unroll
  for (int mi = 0; mi < 4; mi++)
#pragma unroll
    for (int ni = 0; ni < 4; ni++) {
      int col = n0 + wc * 64 + ni * 16 + l15;
      int row = m0 + wr * 64 + mi * 16 + quad * 4;
#pragma unroll
      for (int r = 0; r < 4; r++)
        out[(size_t)(row + r) * 768 + col] = acc[mi][ni][r] + bcol[ni];
    }
}

// ---------------------------------------------------------------------------
// launch
// ---------------------------------------------------------------------------
extern "C" void kernel_launch(void* const* d_in, const int* in_sizes, int n_in,
                              void* d_out, int out_size, void* d_ws, size_t ws_size,
                              hipStream_t stream) {
  const float* x      = (const float*)d_in[0];
  const float* w_qkv  = (const float*)d_in[1];
  const float* b_qkv  = (const float*)d_in[2];
  const float* w_proj = (const float*)d_in[3];
  const float* b_proj = (const float*)d_in[4];
  float* out = (float*)d_out;

  char* ws = (char*)d_ws;
  _Float16* wqkvT  = (_Float16*)(ws);
  _Float16* wprojT = (_Float16*)(ws + 3538944);
  _Float16* Qp     = (_Float16*)(ws + 4718592);
  _Float16* Kp     = (_Float16*)(ws + 29884416);
  _Float16* VTp    = (_Float16*)(ws + 55050240);
  _Float16* Ohp    = (_Float16*)(ws + 80216064);
  // total: 105381888 B (~100 MB)

  cvt_wt2_kernel<<<dim3(24, 96), 256, 0, stream>>>(w_qkv, wqkvT, w_proj, wprojT);
  gemm_qkv_kernel<<<dim3(2304), 256, 0, stream>>>(x, wqkvT, b_qkv, Qp, Kp, VTp);
  attn_kernel<<<dim3(768), 256, 0, stream>>>(Qp, Kp, VTp, Ohp);
  gemm_proj_kernel<<<dim3(768), 256, 0, stream>>>(Ohp, wprojT, b_proj, out);
}

// Round 7
// 329.407 us; speedup vs baseline: 1.4076x; 1.4076x over previous
//
#include <hip/hip_runtime.h>

// ---------------------------------------------------------------------------
// Fused MHA block on gfx950, fp16 MFMA pipeline.
//   qkv GEMM (16384x2304x768, A=fp32 fused-converted) -> per-head flash
//   attention (192 x 1024x1024x64) -> proj GEMM (16384x768x768)
// GEMMs: v_mfma_f32_16x16x32_f16, 128x128 tiles, linear [128][32] LDS,
//        double-buffered, 1 barrier/iter, XCD-swizzled grid, (256,4).
//   qkv A-operand: fp32 global -> regs -> RTN cvt -> ds_write_b128 (fused
//        cvt_x; saves its launch + 62 MB HBM round-trip). A-fragment loads
//        MUST go through LDS: lane-K-contiguity of MFMA frags is
//        uncoalescable from global (r6 regression, 2.3x slower).
//   qkv B-operand + proj both operands: global_load_lds width-16 direct.
//   (256,4): 4 blocks/CU (LDS 4x32=128<=160KB; VGPR 60 fits ~64 cap,
//        no spill expected unlike r3's (256,5) squeeze) -> +33% co-resident
//        waves to hide the per-iter vmcnt drain (m114 overlap mechanism).
// Attention: v_mfma_f32_32x32x16_f16 transposed (S^T = K Q^T, O^T = V^T P^T),
//        P in registers (r1-measured-best version).
// ---------------------------------------------------------------------------

typedef _Float16 half8 __attribute__((ext_vector_type(8)));
typedef _Float16 half4 __attribute__((ext_vector_type(4)));
typedef __fp16   fp16x2 __attribute__((ext_vector_type(2)));
typedef float    f32x4  __attribute__((ext_vector_type(4)));
typedef float    f32x16 __attribute__((ext_vector_type(16)));
typedef unsigned int u32x4 __attribute__((ext_vector_type(4)));

#define DI __device__ __forceinline__

constexpr int   BATCH  = 16;
constexpr int   SEQ    = 1024;
constexpr int   DM     = 768;
constexpr int   NH     = 12;
constexpr int   HD     = 64;
constexpr float SCALE  = 0.125f;          // 1/sqrt(64), folded into Q epilogue
constexpr float LOG2E  = 1.4426950408889634f;

DI void copy16(_Float16* dst, const _Float16* src) {
  *(u32x4*)dst = *(const u32x4*)src;
}

DI int pack_rtz(float a, float b) {
  union { fp16x2 h; int i; } u;
  u.h = __builtin_amdgcn_cvt_pkrtz(a, b);
  return u.i;
}

// async global->LDS, 16 B per lane; lds base must be wave-uniform,
// HW writes lane l at lds + l*16.
DI void gld16(const _Float16* g, _Float16* l) {
  __builtin_amdgcn_global_load_lds(
      (const __attribute__((address_space(1))) void*)g,
      (__attribute__((address_space(3))) void*)l, 16, 0, 0);
}

// ---------------------------------------------------------------------------
// converts (weights only; x conversion is fused into gemm_qkv)
// ---------------------------------------------------------------------------
// both weight transposes in one launch: wt[n*K+k] = w[k*N+n]
__global__ void cvt_wt2_kernel(const float* __restrict__ wq,
                               _Float16* __restrict__ wqT,
                               const float* __restrict__ wp,
                               _Float16* __restrict__ wpT) {
  __shared__ float tile[32][33];
  const int by = blockIdx.y;
  const float* w; _Float16* wt; int N, nb;
  if (by < 72) { w = wq; wt = wqT; N = 2304; nb = by * 32; }
  else         { w = wp; wt = wpT; N = 768;  nb = (by - 72) * 32; }
  const int K = 768;
  int kb = blockIdx.x * 32;
  int tx = threadIdx.x & 31, ty = threadIdx.x >> 5;   // ty 0..7
#pragma unroll
  for (int i = 0; i < 32; i += 8)
    tile[ty + i][tx] = w[(size_t)(kb + ty + i) * N + nb + tx];
  __syncthreads();
#pragma unroll
  for (int i = 0; i < 32; i += 8)
    wt[(size_t)(nb + ty + i) * K + kb + tx] = (_Float16)tile[tx][ty + i];
}

// ---------------------------------------------------------------------------
// GEMM1: qkv = x[16384x768 fp32] @ wqkvT^T + bias, scatter epilogue into
//   Q[bh][n][d] (prescaled by 0.125), K[bh][n][d], VT[bh][d][n]  (fp16)
// A staged via regs + RTN cvt (fused cvt_x); B via global_load_lds.
// ---------------------------------------------------------------------------
__launch_bounds__(256, 4)
__global__ void gemm_qkv_kernel(const float* __restrict__ X,
                                const _Float16* __restrict__ Bt,
                                const float* __restrict__ bias,
                                _Float16* __restrict__ Qo,
                                _Float16* __restrict__ Ko,
                                _Float16* __restrict__ VTo) {
  // 2 bufs x (As 128x32 + Bs 128x32) halves = 32768 B, linear layout
  __shared__ _Float16 sh[16384];
  _Float16* Cs = sh;                 // epilogue alias (64*136 = 8704 halves)
  const int tid  = threadIdx.x;
  // XCD swizzle: all 18 column tiles of one m0 land on one XCD (lin&7)
  const int lin  = blockIdx.x;
  const int xcd  = lin & 7, j = lin >> 3;
  const int ct   = j % 18;             // 0..17 col tiles
  const int m0   = ((j / 18) * 8 + xcd) * 128;
  const int n0   = ct * 128;
  const int w    = tid >> 6, lane = tid & 63;
  const int quad = lane >> 4, l15 = lane & 15;
  const int wr   = w >> 1, wc = w & 1;

  f32x4 acc[4][4] = {};

  // staging geometry: granule g = w*128 + lane (call 0), +64 (call 1 = +16 rows)
  //   -> tile row g>>2, 8-half segment g&3.
  const int g0 = tid + w * 64;
  const int r0 = g0 >> 2, s0 = g0 & 3;
  const float*    gaA = X  + (size_t)(m0 + r0) * 768 + s0 * 8;
  const _Float16* gbB = Bt + (size_t)(n0 + r0) * 768 + s0 * 8;
  const int so   = r0 * 32 + s0 * 8;   // linear [128][32] dest (halves)
  const int ldst = w * 1024;           // gld_lds wave chunk (halves), call 0

  auto CVT_WRITE = [&](float4 a0, float4 a1, float4 a2, float4 a3,
                       _Float16* As) {
    half8 h0, h1;
    h0[0] = (_Float16)a0.x; h0[1] = (_Float16)a0.y;
    h0[2] = (_Float16)a0.z; h0[3] = (_Float16)a0.w;
    h0[4] = (_Float16)a1.x; h0[5] = (_Float16)a1.y;
    h0[6] = (_Float16)a1.z; h0[7] = (_Float16)a1.w;
    h1[0] = (_Float16)a2.x; h1[1] = (_Float16)a2.y;
    h1[2] = (_Float16)a2.z; h1[3] = (_Float16)a2.w;
    h1[4] = (_Float16)a3.x; h1[5] = (_Float16)a3.y;
    h1[6] = (_Float16)a3.z; h1[7] = (_Float16)a3.w;
    *(half8*)(As + so)       = h0;
    *(half8*)(As + so + 512) = h1;    // call 1: +16 rows
  };

  // prologue: tile 0 -> buf 0
  {
    float4 a0 = *(const float4*)(gaA);
    float4 a1 = *(const float4*)(gaA + 4);
    float4 a2 = *(const float4*)(gaA + 16 * 768);
    float4 a3 = *(const float4*)(gaA + 16 * 768 + 4);
    CVT_WRITE(a0, a1, a2, a3, sh);
    gld16(gbB,            sh + 4096 + ldst);
    gld16(gbB + 16 * 768, sh + 4096 + ldst + 512);
  }

  for (int kt = 0; kt < 24; ++kt) {
    __syncthreads();                   // drains vm (B) + lgkm (A writes)
    float4 a0, a1, a2, a3;
    if (kt < 23) {                     // prefetch next tile
      const int k0 = (kt + 1) * 32;
      a0 = *(const float4*)(gaA + k0);
      a1 = *(const float4*)(gaA + k0 + 4);
      a2 = *(const float4*)(gaA + k0 + 16 * 768);
      a3 = *(const float4*)(gaA + k0 + 16 * 768 + 4);
      _Float16* Bsn = sh + ((kt + 1) & 1) * 8192 + 4096;
      gld16(gbB + k0,            Bsn + ldst);
      gld16(gbB + k0 + 16 * 768, Bsn + ldst + 512);
    }

    const _Float16* As = sh + (kt & 1) * 8192;
    const _Float16* Bs = As + 4096;

    half8 af[4], bf[4];
#pragma unroll
    for (int mi = 0; mi < 4; mi++)
      af[mi] = *(const half8*)&As[(wr * 64 + mi * 16 + l15) * 32 + quad * 8];
#pragma unroll
    for (int ni = 0; ni < 4; ni++)
      bf[ni] = *(const half8*)&Bs[(wc * 64 + ni * 16 + l15) * 32 + quad * 8];
#pragma unroll
    for (int mi = 0; mi < 4; mi++)
#pragma unroll
      for (int ni = 0; ni < 4; ni++)
        acc[mi][ni] = __builtin_amdgcn_mfma_f32_16x16x32_f16(
            af[mi], bf[ni], acc[mi][ni], 0, 0, 0);

    if (kt < 23)                       // stage converted A into other buf
      CVT_WRITE(a0, a1, a2, a3, sh + ((kt + 1) & 1) * 8192);
  }
  __syncthreads();

  const float oscale = (ct < 6) ? SCALE : 1.0f;
  float bcol[4];
#pragma unroll
  for (int ni = 0; ni < 4; ni++)
    bcol[ni] = bias[n0 + wc * 64 + ni * 16 + l15];

  const int b     = m0 >> 10;
  const int nrow0 = m0 & 1023;
  const int sec   = ct / 6;            // 0=Q 1=K 2=V
  const int h0    = (ct % 6) * 2;

  // two passes of 64 rows each through Cs
#pragma unroll
  for (int p = 0; p < 2; ++p) {
    if (p) __syncthreads();            // pass-0 reads done before overwrite
    if (wr == p) {
#pragma unroll
      for (int mi = 0; mi < 4; mi++)
#pragma unroll
        for (int ni = 0; ni < 4; ni++) {
          int col = wc * 64 + ni * 16 + l15;
          int row = mi * 16 + quad * 4;
#pragma unroll
          for (int r = 0; r < 4; r++)
            Cs[(row + r) * 136 + col] =
                (_Float16)((acc[mi][ni][r] + bcol[ni]) * oscale);
        }
    }
    __syncthreads();

    if (sec < 2) {
      _Float16* dst = (sec == 0) ? Qo : Ko;
      int row = tid >> 2, seg = tid & 3;
      int hl = seg >> 1, off32 = (seg & 1) * 32;
      _Float16* g = dst +
          ((size_t)((b * NH + h0 + hl) * SEQ + nrow0 + p * 64 + row)) * HD + off32;
      const _Float16* s = &Cs[row * 136 + hl * 64 + off32];
      copy16(g, s);
      copy16(g + 8, s + 8);
      copy16(g + 16, s + 16);
      copy16(g + 24, s + 24);
    } else {
      int c = tid & 127, half = tid >> 7;   // col, row half (32 rows each)
      int hl = c >> 6, d = c & 63;
      _Float16 tmp[32];
#pragma unroll
      for (int jj = 0; jj < 32; jj++) tmp[jj] = Cs[(half * 32 + jj) * 136 + c];
      _Float16* g = VTo + ((size_t)((b * NH + h0 + hl) * HD + d)) * SEQ
                        + nrow0 + p * 64 + half * 32;
#pragma unroll
      for (int jj = 0; jj < 4; jj++)
        copy16(g + jj * 8, (const _Float16*)&tmp[jj * 8]);
    }
  }
}

// ---------------------------------------------------------------------------
// Flash attention, transposed: one wg = (bh, 256-q tile), 4 waves x 64 q.
// S^T = K Q^T (32x32x16 MFMA), P^T kept in registers via half-swap shuffles,
// O^T = V^T P^T.  K-tile 64, double-buffered LDS staging.
// ---------------------------------------------------------------------------
__launch_bounds__(256, 2)
__global__ void attn_kernel(const _Float16* __restrict__ Q,
                            const _Float16* __restrict__ K,
                            const _Float16* __restrict__ VT,
                            _Float16* __restrict__ Oh) {
  __shared__ _Float16 smem[2][2][64 * 72];   // [buf][K/V][64 rows][72]
  _Float16* OLds = &smem[0][0][0];           // aliased epilogue staging (36864B)

  const int tid = threadIdx.x;
  const int i   = blockIdx.x;
  const int bh  = (i & 7) * 24 + ((i >> 3) >> 2);   // XCD swizzle: 4 q-blocks
  const int q0  = ((i >> 3) & 3) * 256;             //  of one bh share an XCD
  const int b   = bh / NH, hh = bh - b * NH;
  const int w   = tid >> 6, lane = tid & 63;
  const int l31 = lane & 31, h = lane >> 5;

  const _Float16* Qg = Q  + (size_t)bh * SEQ * HD;
  const _Float16* Kg = K  + (size_t)bh * SEQ * HD;
  const _Float16* Vg = VT + (size_t)bh * HD * SEQ;

  // persistent Q B-frags: qb[N][s] ; B[k=d][n=q] read from Q[q][d] row-major
  half8 qb[2][4];
#pragma unroll
  for (int N = 0; N < 2; N++) {
    const _Float16* qrow = Qg + (size_t)(q0 + w * 64 + N * 32 + l31) * HD + h * 8;
#pragma unroll
    for (int s = 0; s < 4; s++)
      qb[N][s] = *(const half8*)(qrow + s * 16);
  }

  // staging: threads 0-127 stage K tile, 128-255 stage V^T tile (64B each)
  const int  sr  = (tid & 127) >> 1;
  const int  sp  = tid & 1;
  const bool isK = tid < 128;
  const _Float16* sg = isK ? (Kg + sr * HD + sp * 32)
                           : (Vg + (size_t)sr * SEQ + sp * 32);
  const int sstep = isK ? 64 * HD : 64;
  const int soff  = (isK ? 0 : 64 * 72) + sr * 72 + sp * 32;

  u32x4 pf[4];
#pragma unroll
  for (int c = 0; c < 4; c++) pf[c] = *(const u32x4*)(sg + c * 8);
#pragma unroll
  for (int c = 0; c < 4; c++) *(u32x4*)(&smem[0][0][0] + soff + c * 8) = pf[c];

  f32x16 of[2][2];
#pragma unroll
  for (int D = 0; D < 2; D++)
#pragma unroll
    for (int N = 0; N < 2; N++)
#pragma unroll
      for (int r = 0; r < 16; r++) of[D][N][r] = 0.f;
  float m_[2] = {-1e30f, -1e30f}, l_[2] = {0.f, 0.f};

  for (int kt = 0; kt < 16; ++kt) {
    if (kt < 15) {
      const _Float16* nsg = sg + (kt + 1) * sstep;
#pragma unroll
      for (int c = 0; c < 4; c++) pf[c] = *(const u32x4*)(nsg + c * 8);
    }
    __syncthreads();
    const _Float16* Ks = &smem[kt & 1][0][0];
    const _Float16* Vs = &smem[kt & 1][1][0];

    // S^T = K Q^T : 2 m-frags (64 keys) x 2 n-frags (64 q)
    f32x16 sf[2][2];
#pragma unroll
    for (int M = 0; M < 2; M++)
#pragma unroll
      for (int N = 0; N < 2; N++)
#pragma unroll
        for (int r = 0; r < 16; r++) sf[M][N][r] = 0.f;
#pragma unroll
    for (int s = 0; s < 4; s++) {
      half8 ka0 = *(const half8*)&Ks[l31 * 72 + s * 16 + h * 8];
      half8 ka1 = *(const half8*)&Ks[(32 + l31) * 72 + s * 16 + h * 8];
#pragma unroll
      for (int N = 0; N < 2; N++) {
        sf[0][N] = __builtin_amdgcn_mfma_f32_32x32x16_f16(ka0, qb[N][s], sf[0][N], 0, 0, 0);
        sf[1][N] = __builtin_amdgcn_mfma_f32_32x32x16_f16(ka1, qb[N][s], sf[1][N], 0, 0, 0);
      }
    }

    // online softmax; stats are per q = per lane (col of S^T)
    float alpha[2], c1[2], tsum[2];
#pragma unroll
    for (int N = 0; N < 2; N++) {
      float tmax = -1e30f;
#pragma unroll
      for (int r = 0; r < 16; r++)
        tmax = fmaxf(tmax, fmaxf(sf[0][N][r], sf[1][N][r]));
      tmax = fmaxf(tmax, __shfl_xor(tmax, 32, 64));
      float mnew = fmaxf(m_[N], tmax);
      alpha[N] = __builtin_amdgcn_exp2f((m_[N] - mnew) * LOG2E);
      m_[N] = mnew;
      c1[N] = mnew * LOG2E;
      tsum[N] = 0.f;
    }

    // exp -> P^T, pack fp16 pairs into dwords (kept in registers)
    int pdw[2][2][8];
#pragma unroll
    for (int M = 0; M < 2; M++)
#pragma unroll
      for (int N = 0; N < 2; N++) {
#pragma unroll
        for (int r = 0; r < 16; r++) {
          float p = __builtin_amdgcn_exp2f(sf[M][N][r] * LOG2E - c1[N]);
          sf[M][N][r] = p;
          tsum[N] += p;
        }
#pragma unroll
        for (int u = 0; u < 8; u++)
          pdw[M][N][u] = pack_rtz(sf[M][N][2 * u], sf[M][N][2 * u + 1]);
      }
#pragma unroll
    for (int N = 0; N < 2; N++) {
      tsum[N] += __shfl_xor(tsum[N], 32, 64);
      l_[N] = l_[N] * alpha[N] + tsum[N];
    }
#pragma unroll
    for (int D = 0; D < 2; D++)
#pragma unroll
      for (int N = 0; N < 2; N++)
#pragma unroll
        for (int r = 0; r < 16; r++) of[D][N][r] *= alpha[N];

    // O^T += V^T P^T ; P^T B-frags assembled from pdw via lane^32 half-swap
#pragma unroll
    for (int t = 0; t < 4; ++t) {
      const int M = t >> 1, s2 = (t & 1) * 4;
      half8 va0 = *(const half8*)&Vs[l31 * 72 + t * 16 + h * 8];
      half8 va1 = *(const half8*)&Vs[(32 + l31) * 72 + t * 16 + h * 8];
#pragma unroll
      for (int N = 0; N < 2; N++) {
        int a0 = pdw[M][N][s2 + 0], a1 = pdw[M][N][s2 + 1];
        int a2 = pdw[M][N][s2 + 2], a3 = pdw[M][N][s2 + 3];
        int e0 = h ? a0 : a2, e1 = h ? a1 : a3;
        int r0 = __shfl_xor(e0, 32, 64), r1 = __shfl_xor(e1, 32, 64);
        union { u32x4 u; half8 hv; } bb;
        bb.u[0] = h ? r0 : a0; bb.u[1] = h ? r1 : a1;
        bb.u[2] = h ? a2 : r0; bb.u[3] = h ? a3 : r1;
        of[0][N] = __builtin_amdgcn_mfma_f32_32x32x16_f16(va0, bb.hv, of[0][N], 0, 0, 0);
        of[1][N] = __builtin_amdgcn_mfma_f32_32x32x16_f16(va1, bb.hv, of[1][N], 0, 0, 0);
      }
    }

    if (kt < 15) {
      _Float16* dst = &smem[(kt + 1) & 1][0][0] + soff;
#pragma unroll
      for (int c = 0; c < 4; c++) *(u32x4*)(dst + c * 8) = pf[c];
    }
  }

  // epilogue: normalize, transpose O^T -> O through LDS, coalesced store
  __syncthreads();                       // all waves done with staging buffers
  float inv[2] = {1.0f / l_[0], 1.0f / l_[1]};
  int* OW = (int*)OLds;
#pragma unroll
  for (int N = 0; N < 2; N++) {
    const int q_local = w * 64 + N * 32 + l31;
#pragma unroll
    for (int D = 0; D < 2; D++)
#pragma unroll
      for (int u = 0; u < 8; u++) {
        int v = pack_rtz(of[D][N][2 * u] * inv[N], of[D][N][2 * u + 1] * inv[N]);
        int dwi = 16 * D + 4 * (u >> 1) + (u & 1) + 2 * h;
        OW[q_local * 36 + dwi] = v;
      }
  }
  __syncthreads();
#pragma unroll
  for (int p = 0; p < 8; p++) {
    int q = p * 32 + (tid >> 3), c = tid & 7;
    *(u32x4*)(Oh + (size_t)(b * SEQ + q0 + q) * DM + hh * HD + c * 8) =
        *(const u32x4*)&OLds[q * 72 + c * 8];
  }
}

// ---------------------------------------------------------------------------
// GEMM2: out = Oh[16384x768] @ wprojT^T + bias  (fp32 direct stores)
// ---------------------------------------------------------------------------
__launch_bounds__(256, 4)
__global__ void gemm_proj_kernel(const _Float16* __restrict__ A,
                                 const _Float16* __restrict__ Bt,
                                 const float* __restrict__ bias,
                                 float* __restrict__ out) {
  __shared__ _Float16 sh[16384];     // 2 bufs x (As 128x32 + Bs 128x32), linear
  const int tid  = threadIdx.x;
  // XCD swizzle: all 6 column tiles of one m0 on one XCD
  const int lin  = blockIdx.x;
  const int xcd  = lin & 7, j = lin >> 3;
  const int ct   = j % 6;
  const int m0   = ((j / 6) * 8 + xcd) * 128;
  const int n0   = ct * 128;
  const int w    = tid >> 6, lane = tid & 63;
  const int quad = lane >> 4, l15 = lane & 15;
  const int wr   = w >> 1, wc = w & 1;

  f32x4 acc[4][4] = {};

  const int g0 = tid + w * 64;
  const int r0 = g0 >> 2, s0 = g0 & 3;
  const _Float16* gaA = A  + (size_t)(m0 + r0) * 768 + s0 * 8;
  const _Float16* gaB = Bt + (size_t)(n0 + r0) * 768 + s0 * 8;
  const int ldst = w * 1024;

  auto STAGE = [&](int buf, int kt) {
    _Float16* As = sh + buf * 8192;
    _Float16* Bs = As + 4096;
    const _Float16* a = gaA + kt * 32;
    const _Float16* b = gaB + kt * 32;
    gld16(a,            As + ldst);
    gld16(a + 16 * 768, As + ldst + 512);
    gld16(b,            Bs + ldst);
    gld16(b + 16 * 768, Bs + ldst + 512);
  };

  STAGE(0, 0);

  for (int kt = 0; kt < 24; ++kt) {
    __syncthreads();
    if (kt < 23) STAGE((kt + 1) & 1, kt + 1);

    const _Float16* As = sh + (kt & 1) * 8192;
    const _Float16* Bs = As + 4096;

    half8 af[4], bf[4];
#pragma unroll
    for (int mi = 0; mi < 4; mi++)
      af[mi] = *(const half8*)&As[(wr * 64 + mi * 16 + l15) * 32 + quad * 8];
#pragma unroll
    for (int ni = 0; ni < 4; ni++)
      bf[ni] = *(const half8*)&Bs[(wc * 64 + ni * 16 + l15) * 32 + quad * 8];
#pragma unroll
    for (int mi = 0; mi < 4; mi++)
#pragma unroll
      for (int ni = 0; ni < 4; ni++)
        acc[mi][ni] = __builtin_amdgcn_mfma_f32_16x16x32_f16(
            af[mi], bf[ni], acc[mi][ni], 0, 0, 0);
  }

  float bcol[4];
#pragma unroll
  for (int ni = 0; ni < 4; ni++)
    bcol[ni] = bias[n0 + wc * 64 + ni * 16 + l15];
#pragma unroll
  for (int mi = 0; mi < 4; mi++)
#pragma unroll
    for (int ni = 0; ni < 4; ni++) {
      int col = n0 + wc * 64 + ni * 16 + l15;
      int row = m0 + wr * 64 + mi * 16 + quad * 4;
#pragma unroll
      for (int r = 0; r < 4; r++)
        out[(size_t)(row + r) * 768 + col] = acc[mi][ni][r] + bcol[ni];
    }
}

// ---------------------------------------------------------------------------
// launch
// ---------------------------------------------------------------------------
extern "C" void kernel_launch(void* const* d_in, const int* in_sizes, int n_in,
                              void* d_out, int out_size, void* d_ws, size_t ws_size,
                              hipStream_t stream) {
  const float* x      = (const float*)d_in[0];
  const float* w_qkv  = (const float*)d_in[1];
  const float* b_qkv  = (const float*)d_in[2];
  const float* w_proj = (const float*)d_in[3];
  const float* b_proj = (const float*)d_in[4];
  float* out = (float*)d_out;

  char* ws = (char*)d_ws;
  _Float16* wqkvT  = (_Float16*)(ws);
  _Float16* wprojT = (_Float16*)(ws + 3538944);
  _Float16* Qp     = (_Float16*)(ws + 4718592);
  _Float16* Kp     = (_Float16*)(ws + 29884416);
  _Float16* VTp    = (_Float16*)(ws + 55050240);
  _Float16* Ohp    = (_Float16*)(ws + 80216064);
  // total: 105381888 B (~100 MB)

  cvt_wt2_kernel<<<dim3(24, 96), 256, 0, stream>>>(w_qkv, wqkvT, w_proj, wprojT);
  gemm_qkv_kernel<<<dim3(2304), 256, 0, stream>>>(x, wqkvT, b_qkv, Qp, Kp, VTp);
  attn_kernel<<<dim3(768), 256, 0, stream>>>(Qp, Kp, VTp, Ohp);
  gemm_proj_kernel<<<dim3(768), 256, 0, stream>>>(Ohp, wprojT, b_proj, out);
}

// Round 8
// 302.458 us; speedup vs baseline: 1.5330x; 1.0891x over previous
//
#include <hip/hip_runtime.h>

// ---------------------------------------------------------------------------
// Fused MHA block on gfx950, fp16 MFMA pipeline.  (r5 measured-best, 303.5us)
//   qkv GEMM (16384x2304x768, A=fp32 fused-converted) -> per-head flash
//   attention (192 x 1024x1024x64) -> proj GEMM (16384x768x768)
// GEMMs: v_mfma_f32_16x16x32_f16, 128x128 tiles, linear [128][32] LDS,
//        double-buffered, 1 barrier/iter, XCD-swizzled grid, (256,3).
//   NOTE launch-bounds ledger: (256,3) best; (256,4) regressed (scheduling,
//   r7: MfmaUtil 20->16 at flat occupancy); (256,5) spilled (r3: VGPR 48).
//   qkv A-operand: fp32 global -> regs -> RTN cvt -> ds_write_b128 (fuses
//        the former cvt_x kernel; saves its launch + 62 MB HBM round-trip).
//        A-fragment loads MUST go through LDS: lane-K-contiguity of MFMA
//        frags is uncoalescable from global (r6: 2.3x regression).
//   qkv B-operand + proj both operands: global_load_lds width-16 direct.
// Attention: v_mfma_f32_32x32x16_f16 transposed (S^T = K Q^T, O^T = V^T P^T),
//        P in registers (r1-measured-best; T13 defer-max & T5 setprio
//        measured null here in r4).
// ---------------------------------------------------------------------------

typedef _Float16 half8 __attribute__((ext_vector_type(8)));
typedef _Float16 half4 __attribute__((ext_vector_type(4)));
typedef __fp16   fp16x2 __attribute__((ext_vector_type(2)));
typedef float    f32x4  __attribute__((ext_vector_type(4)));
typedef float    f32x16 __attribute__((ext_vector_type(16)));
typedef unsigned int u32x4 __attribute__((ext_vector_type(4)));

#define DI __device__ __forceinline__

constexpr int   BATCH  = 16;
constexpr int   SEQ    = 1024;
constexpr int   DM     = 768;
constexpr int   NH     = 12;
constexpr int   HD     = 64;
constexpr float SCALE  = 0.125f;          // 1/sqrt(64), folded into Q epilogue
constexpr float LOG2E  = 1.4426950408889634f;

DI void copy16(_Float16* dst, const _Float16* src) {
  *(u32x4*)dst = *(const u32x4*)src;
}

DI int pack_rtz(float a, float b) {
  union { fp16x2 h; int i; } u;
  u.h = __builtin_amdgcn_cvt_pkrtz(a, b);
  return u.i;
}

// async global->LDS, 16 B per lane; lds base must be wave-uniform,
// HW writes lane l at lds + l*16.
DI void gld16(const _Float16* g, _Float16* l) {
  __builtin_amdgcn_global_load_lds(
      (const __attribute__((address_space(1))) void*)g,
      (__attribute__((address_space(3))) void*)l, 16, 0, 0);
}

// ---------------------------------------------------------------------------
// converts (weights only; x conversion is fused into gemm_qkv)
// ---------------------------------------------------------------------------
// both weight transposes in one launch: wt[n*K+k] = w[k*N+n]
__global__ void cvt_wt2_kernel(const float* __restrict__ wq,
                               _Float16* __restrict__ wqT,
                               const float* __restrict__ wp,
                               _Float16* __restrict__ wpT) {
  __shared__ float tile[32][33];
  const int by = blockIdx.y;
  const float* w; _Float16* wt; int N, nb;
  if (by < 72) { w = wq; wt = wqT; N = 2304; nb = by * 32; }
  else         { w = wp; wt = wpT; N = 768;  nb = (by - 72) * 32; }
  const int K = 768;
  int kb = blockIdx.x * 32;
  int tx = threadIdx.x & 31, ty = threadIdx.x >> 5;   // ty 0..7
#pragma unroll
  for (int i = 0; i < 32; i += 8)
    tile[ty + i][tx] = w[(size_t)(kb + ty + i) * N + nb + tx];
  __syncthreads();
#pragma unroll
  for (int i = 0; i < 32; i += 8)
    wt[(size_t)(nb + ty + i) * K + kb + tx] = (_Float16)tile[tx][ty + i];
}

// ---------------------------------------------------------------------------
// GEMM1: qkv = x[16384x768 fp32] @ wqkvT^T + bias, scatter epilogue into
//   Q[bh][n][d] (prescaled by 0.125), K[bh][n][d], VT[bh][d][n]  (fp16)
// A staged via regs + RTN cvt (fused cvt_x); B via global_load_lds.
// ---------------------------------------------------------------------------
__launch_bounds__(256, 3)
__global__ void gemm_qkv_kernel(const float* __restrict__ X,
                                const _Float16* __restrict__ Bt,
                                const float* __restrict__ bias,
                                _Float16* __restrict__ Qo,
                                _Float16* __restrict__ Ko,
                                _Float16* __restrict__ VTo) {
  // 2 bufs x (As 128x32 + Bs 128x32) halves = 32768 B, linear layout
  __shared__ _Float16 sh[16384];
  _Float16* Cs = sh;                 // epilogue alias (64*136 = 8704 halves)
  const int tid  = threadIdx.x;
  // XCD swizzle: all 18 column tiles of one m0 land on one XCD (lin&7)
  const int lin  = blockIdx.x;
  const int xcd  = lin & 7, j = lin >> 3;
  const int ct   = j % 18;             // 0..17 col tiles
  const int m0   = ((j / 18) * 8 + xcd) * 128;
  const int n0   = ct * 128;
  const int w    = tid >> 6, lane = tid & 63;
  const int quad = lane >> 4, l15 = lane & 15;
  const int wr   = w >> 1, wc = w & 1;

  f32x4 acc[4][4] = {};

  // staging geometry: granule g = w*128 + lane (call 0), +64 (call 1 = +16 rows)
  //   -> tile row g>>2, 8-half segment g&3.
  const int g0 = tid + w * 64;
  const int r0 = g0 >> 2, s0 = g0 & 3;
  const float*    gaA = X  + (size_t)(m0 + r0) * 768 + s0 * 8;
  const _Float16* gbB = Bt + (size_t)(n0 + r0) * 768 + s0 * 8;
  const int so   = r0 * 32 + s0 * 8;   // linear [128][32] dest (halves)
  const int ldst = w * 1024;           // gld_lds wave chunk (halves), call 0

  auto CVT_WRITE = [&](float4 a0, float4 a1, float4 a2, float4 a3,
                       _Float16* As) {
    half8 h0, h1;
    h0[0] = (_Float16)a0.x; h0[1] = (_Float16)a0.y;
    h0[2] = (_Float16)a0.z; h0[3] = (_Float16)a0.w;
    h0[4] = (_Float16)a1.x; h0[5] = (_Float16)a1.y;
    h0[6] = (_Float16)a1.z; h0[7] = (_Float16)a1.w;
    h1[0] = (_Float16)a2.x; h1[1] = (_Float16)a2.y;
    h1[2] = (_Float16)a2.z; h1[3] = (_Float16)a2.w;
    h1[4] = (_Float16)a3.x; h1[5] = (_Float16)a3.y;
    h1[6] = (_Float16)a3.z; h1[7] = (_Float16)a3.w;
    *(half8*)(As + so)       = h0;
    *(half8*)(As + so + 512) = h1;    // call 1: +16 rows
  };

  // prologue: tile 0 -> buf 0
  {
    float4 a0 = *(const float4*)(gaA);
    float4 a1 = *(const float4*)(gaA + 4);
    float4 a2 = *(const float4*)(gaA + 16 * 768);
    float4 a3 = *(const float4*)(gaA + 16 * 768 + 4);
    CVT_WRITE(a0, a1, a2, a3, sh);
    gld16(gbB,            sh + 4096 + ldst);
    gld16(gbB + 16 * 768, sh + 4096 + ldst + 512);
  }

  for (int kt = 0; kt < 24; ++kt) {
    __syncthreads();                   // drains vm (B) + lgkm (A writes)
    float4 a0, a1, a2, a3;
    if (kt < 23) {                     // prefetch next tile
      const int k0 = (kt + 1) * 32;
      a0 = *(const float4*)(gaA + k0);
      a1 = *(const float4*)(gaA + k0 + 4);
      a2 = *(const float4*)(gaA + k0 + 16 * 768);
      a3 = *(const float4*)(gaA + k0 + 16 * 768 + 4);
      _Float16* Bsn = sh + ((kt + 1) & 1) * 8192 + 4096;
      gld16(gbB + k0,            Bsn + ldst);
      gld16(gbB + k0 + 16 * 768, Bsn + ldst + 512);
    }

    const _Float16* As = sh + (kt & 1) * 8192;
    const _Float16* Bs = As + 4096;

    half8 af[4], bf[4];
#pragma unroll
    for (int mi = 0; mi < 4; mi++)
      af[mi] = *(const half8*)&As[(wr * 64 + mi * 16 + l15) * 32 + quad * 8];
#pragma unroll
    for (int ni = 0; ni < 4; ni++)
      bf[ni] = *(const half8*)&Bs[(wc * 64 + ni * 16 + l15) * 32 + quad * 8];
#pragma unroll
    for (int mi = 0; mi < 4; mi++)
#pragma unroll
      for (int ni = 0; ni < 4; ni++)
        acc[mi][ni] = __builtin_amdgcn_mfma_f32_16x16x32_f16(
            af[mi], bf[ni], acc[mi][ni], 0, 0, 0);

    if (kt < 23)                       // stage converted A into other buf
      CVT_WRITE(a0, a1, a2, a3, sh + ((kt + 1) & 1) * 8192);
  }
  __syncthreads();

  const float oscale = (ct < 6) ? SCALE : 1.0f;
  float bcol[4];
#pragma unroll
  for (int ni = 0; ni < 4; ni++)
    bcol[ni] = bias[n0 + wc * 64 + ni * 16 + l15];

  const int b     = m0 >> 10;
  const int nrow0 = m0 & 1023;
  const int sec   = ct / 6;            // 0=Q 1=K 2=V
  const int h0    = (ct % 6) * 2;

  // two passes of 64 rows each through Cs
#pragma unroll
  for (int p = 0; p < 2; ++p) {
    if (p) __syncthreads();            // pass-0 reads done before overwrite
    if (wr == p) {
#pragma unroll
      for (int mi = 0; mi < 4; mi++)
#pragma unroll
        for (int ni = 0; ni < 4; ni++) {
          int col = wc * 64 + ni * 16 + l15;
          int row = mi * 16 + quad * 4;
#pragma unroll
          for (int r = 0; r < 4; r++)
            Cs[(row + r) * 136 + col] =
                (_Float16)((acc[mi][ni][r] + bcol[ni]) * oscale);
        }
    }
    __syncthreads();

    if (sec < 2) {
      _Float16* dst = (sec == 0) ? Qo : Ko;
      int row = tid >> 2, seg = tid & 3;
      int hl = seg >> 1, off32 = (seg & 1) * 32;
      _Float16* g = dst +
          ((size_t)((b * NH + h0 + hl) * SEQ + nrow0 + p * 64 + row)) * HD + off32;
      const _Float16* s = &Cs[row * 136 + hl * 64 + off32];
      copy16(g, s);
      copy16(g + 8, s + 8);
      copy16(g + 16, s + 16);
      copy16(g + 24, s + 24);
    } else {
      int c = tid & 127, half = tid >> 7;   // col, row half (32 rows each)
      int hl = c >> 6, d = c & 63;
      _Float16 tmp[32];
#pragma unroll
      for (int jj = 0; jj < 32; jj++) tmp[jj] = Cs[(half * 32 + jj) * 136 + c];
      _Float16* g = VTo + ((size_t)((b * NH + h0 + hl) * HD + d)) * SEQ
                        + nrow0 + p * 64 + half * 32;
#pragma unroll
      for (int jj = 0; jj < 4; jj++)
        copy16(g + jj * 8, (const _Float16*)&tmp[jj * 8]);
    }
  }
}

// ---------------------------------------------------------------------------
// Flash attention, transposed: one wg = (bh, 256-q tile), 4 waves x 64 q.
// S^T = K Q^T (32x32x16 MFMA), P^T kept in registers via half-swap shuffles,
// O^T = V^T P^T.  K-tile 64, double-buffered LDS staging.
// ---------------------------------------------------------------------------
__launch_bounds__(256, 2)
__global__ void attn_kernel(const _Float16* __restrict__ Q,
                            const _Float16* __restrict__ K,
                            const _Float16* __restrict__ VT,
                            _Float16* __restrict__ Oh) {
  __shared__ _Float16 smem[2][2][64 * 72];   // [buf][K/V][64 rows][72]
  _Float16* OLds = &smem[0][0][0];           // aliased epilogue staging (36864B)

  const int tid = threadIdx.x;
  const int i   = blockIdx.x;
  const int bh  = (i & 7) * 24 + ((i >> 3) >> 2);   // XCD swizzle: 4 q-blocks
  const int q0  = ((i >> 3) & 3) * 256;             //  of one bh share an XCD
  const int b   = bh / NH, hh = bh - b * NH;
  const int w   = tid >> 6, lane = tid & 63;
  const int l31 = lane & 31, h = lane >> 5;

  const _Float16* Qg = Q  + (size_t)bh * SEQ * HD;
  const _Float16* Kg = K  + (size_t)bh * SEQ * HD;
  const _Float16* Vg = VT + (size_t)bh * HD * SEQ;

  // persistent Q B-frags: qb[N][s] ; B[k=d][n=q] read from Q[q][d] row-major
  half8 qb[2][4];
#pragma unroll
  for (int N = 0; N < 2; N++) {
    const _Float16* qrow = Qg + (size_t)(q0 + w * 64 + N * 32 + l31) * HD + h * 8;
#pragma unroll
    for (int s = 0; s < 4; s++)
      qb[N][s] = *(const half8*)(qrow + s * 16);
  }

  // staging: threads 0-127 stage K tile, 128-255 stage V^T tile (64B each)
  const int  sr  = (tid & 127) >> 1;
  const int  sp  = tid & 1;
  const bool isK = tid < 128;
  const _Float16* sg = isK ? (Kg + sr * HD + sp * 32)
                           : (Vg + (size_t)sr * SEQ + sp * 32);
  const int sstep = isK ? 64 * HD : 64;
  const int soff  = (isK ? 0 : 64 * 72) + sr * 72 + sp * 32;

  u32x4 pf[4];
#pragma unroll
  for (int c = 0; c < 4; c++) pf[c] = *(const u32x4*)(sg + c * 8);
#pragma unroll
  for (int c = 0; c < 4; c++) *(u32x4*)(&smem[0][0][0] + soff + c * 8) = pf[c];

  f32x16 of[2][2];
#pragma unroll
  for (int D = 0; D < 2; D++)
#pragma unroll
    for (int N = 0; N < 2; N++)
#pragma unroll
      for (int r = 0; r < 16; r++) of[D][N][r] = 0.f;
  float m_[2] = {-1e30f, -1e30f}, l_[2] = {0.f, 0.f};

  for (int kt = 0; kt < 16; ++kt) {
    if (kt < 15) {
      const _Float16* nsg = sg + (kt + 1) * sstep;
#pragma unroll
      for (int c = 0; c < 4; c++) pf[c] = *(const u32x4*)(nsg + c * 8);
    }
    __syncthreads();
    const _Float16* Ks = &smem[kt & 1][0][0];
    const _Float16* Vs = &smem[kt & 1][1][0];

    // S^T = K Q^T : 2 m-frags (64 keys) x 2 n-frags (64 q)
    f32x16 sf[2][2];
#pragma unroll
    for (int M = 0; M < 2; M++)
#pragma unroll
      for (int N = 0; N < 2; N++)
#pragma unroll
        for (int r = 0; r < 16; r++) sf[M][N][r] = 0.f;
#pragma unroll
    for (int s = 0; s < 4; s++) {
      half8 ka0 = *(const half8*)&Ks[l31 * 72 + s * 16 + h * 8];
      half8 ka1 = *(const half8*)&Ks[(32 + l31) * 72 + s * 16 + h * 8];
#pragma unroll
      for (int N = 0; N < 2; N++) {
        sf[0][N] = __builtin_amdgcn_mfma_f32_32x32x16_f16(ka0, qb[N][s], sf[0][N], 0, 0, 0);
        sf[1][N] = __builtin_amdgcn_mfma_f32_32x32x16_f16(ka1, qb[N][s], sf[1][N], 0, 0, 0);
      }
    }

    // online softmax; stats are per q = per lane (col of S^T)
    float alpha[2], c1[2], tsum[2];
#pragma unroll
    for (int N = 0; N < 2; N++) {
      float tmax = -1e30f;
#pragma unroll
      for (int r = 0; r < 16; r++)
        tmax = fmaxf(tmax, fmaxf(sf[0][N][r], sf[1][N][r]));
      tmax = fmaxf(tmax, __shfl_xor(tmax, 32, 64));
      float mnew = fmaxf(m_[N], tmax);
      alpha[N] = __builtin_amdgcn_exp2f((m_[N] - mnew) * LOG2E);
      m_[N] = mnew;
      c1[N] = mnew * LOG2E;
      tsum[N] = 0.f;
    }

    // exp -> P^T, pack fp16 pairs into dwords (kept in registers)
    int pdw[2][2][8];
#pragma unroll
    for (int M = 0; M < 2; M++)
#pragma unroll
      for (int N = 0; N < 2; N++) {
#pragma unroll
        for (int r = 0; r < 16; r++) {
          float p = __builtin_amdgcn_exp2f(sf[M][N][r] * LOG2E - c1[N]);
          sf[M][N][r] = p;
          tsum[N] += p;
        }
#pragma unroll
        for (int u = 0; u < 8; u++)
          pdw[M][N][u] = pack_rtz(sf[M][N][2 * u], sf[M][N][2 * u + 1]);
      }
#pragma unroll
    for (int N = 0; N < 2; N++) {
      tsum[N] += __shfl_xor(tsum[N], 32, 64);
      l_[N] = l_[N] * alpha[N] + tsum[N];
    }
#pragma unroll
    for (int D = 0; D < 2; D++)
#pragma unroll
      for (int N = 0; N < 2; N++)
#pragma unroll
        for (int r = 0; r < 16; r++) of[D][N][r] *= alpha[N];

    // O^T += V^T P^T ; P^T B-frags assembled from pdw via lane^32 half-swap
#pragma unroll
    for (int t = 0; t < 4; ++t) {
      const int M = t >> 1, s2 = (t & 1) * 4;
      half8 va0 = *(const half8*)&Vs[l31 * 72 + t * 16 + h * 8];
      half8 va1 = *(const half8*)&Vs[(32 + l31) * 72 + t * 16 + h * 8];
#pragma unroll
      for (int N = 0; N < 2; N++) {
        int a0 = pdw[M][N][s2 + 0], a1 = pdw[M][N][s2 + 1];
        int a2 = pdw[M][N][s2 + 2], a3 = pdw[M][N][s2 + 3];
        int e0 = h ? a0 : a2, e1 = h ? a1 : a3;
        int r0 = __shfl_xor(e0, 32, 64), r1 = __shfl_xor(e1, 32, 64);
        union { u32x4 u; half8 hv; } bb;
        bb.u[0] = h ? r0 : a0; bb.u[1] = h ? r1 : a1;
        bb.u[2] = h ? a2 : r0; bb.u[3] = h ? a3 : r1;
        of[0][N] = __builtin_amdgcn_mfma_f32_32x32x16_f16(va0, bb.hv, of[0][N], 0, 0, 0);
        of[1][N] = __builtin_amdgcn_mfma_f32_32x32x16_f16(va1, bb.hv, of[1][N], 0, 0, 0);
      }
    }

    if (kt < 15) {
      _Float16* dst = &smem[(kt + 1) & 1][0][0] + soff;
#pragma unroll
      for (int c = 0; c < 4; c++) *(u32x4*)(dst + c * 8) = pf[c];
    }
  }

  // epilogue: normalize, transpose O^T -> O through LDS, coalesced store
  __syncthreads();                       // all waves done with staging buffers
  float inv[2] = {1.0f / l_[0], 1.0f / l_[1]};
  int* OW = (int*)OLds;
#pragma unroll
  for (int N = 0; N < 2; N++) {
    const int q_local = w * 64 + N * 32 + l31;
#pragma unroll
    for (int D = 0; D < 2; D++)
#pragma unroll
      for (int u = 0; u < 8; u++) {
        int v = pack_rtz(of[D][N][2 * u] * inv[N], of[D][N][2 * u + 1] * inv[N]);
        int dwi = 16 * D + 4 * (u >> 1) + (u & 1) + 2 * h;
        OW[q_local * 36 + dwi] = v;
      }
  }
  __syncthreads();
#pragma unroll
  for (int p = 0; p < 8; p++) {
    int q = p * 32 + (tid >> 3), c = tid & 7;
    *(u32x4*)(Oh + (size_t)(b * SEQ + q0 + q) * DM + hh * HD + c * 8) =
        *(const u32x4*)&OLds[q * 72 + c * 8];
  }
}

// ---------------------------------------------------------------------------
// GEMM2: out = Oh[16384x768] @ wprojT^T + bias  (fp32 direct stores)
// ---------------------------------------------------------------------------
__launch_bounds__(256, 3)
__global__ void gemm_proj_kernel(const _Float16* __restrict__ A,
                                 const _Float16* __restrict__ Bt,
                                 const float* __restrict__ bias,
                                 float* __restrict__ out) {
  __shared__ _Float16 sh[16384];     // 2 bufs x (As 128x32 + Bs 128x32), linear
  const int tid  = threadIdx.x;
  // XCD swizzle: all 6 column tiles of one m0 on one XCD
  const int lin  = blockIdx.x;
  const int xcd  = lin & 7, j = lin >> 3;
  const int ct   = j % 6;
  const int m0   = ((j / 6) * 8 + xcd) * 128;
  const int n0   = ct * 128;
  const int w    = tid >> 6, lane = tid & 63;
  const int quad = lane >> 4, l15 = lane & 15;
  const int wr   = w >> 1, wc = w & 1;

  f32x4 acc[4][4] = {};

  const int g0 = tid + w * 64;
  const int r0 = g0 >> 2, s0 = g0 & 3;
  const _Float16* gaA = A  + (size_t)(m0 + r0) * 768 + s0 * 8;
  const _Float16* gaB = Bt + (size_t)(n0 + r0) * 768 + s0 * 8;
  const int ldst = w * 1024;

  auto STAGE = [&](int buf, int kt) {
    _Float16* As = sh + buf * 8192;
    _Float16* Bs = As + 4096;
    const _Float16* a = gaA + kt * 32;
    const _Float16* b = gaB + kt * 32;
    gld16(a,            As + ldst);
    gld16(a + 16 * 768, As + ldst + 512);
    gld16(b,            Bs + ldst);
    gld16(b + 16 * 768, Bs + ldst + 512);
  };

  STAGE(0, 0);

  for (int kt = 0; kt < 24; ++kt) {
    __syncthreads();
    if (kt < 23) STAGE((kt + 1) & 1, kt + 1);

    const _Float16* As = sh + (kt & 1) * 8192;
    const _Float16* Bs = As + 4096;

    half8 af[4], bf[4];
#pragma unroll
    for (int mi = 0; mi < 4; mi++)
      af[mi] = *(const half8*)&As[(wr * 64 + mi * 16 + l15) * 32 + quad * 8];
#pragma unroll
    for (int ni = 0; ni < 4; ni++)
      bf[ni] = *(const half8*)&Bs[(wc * 64 + ni * 16 + l15) * 32 + quad * 8];
#pragma unroll
    for (int mi = 0; mi < 4; mi++)
#pragma unroll
      for (int ni = 0; ni < 4; ni++)
        acc[mi][ni] = __builtin_amdgcn_mfma_f32_16x16x32_f16(
            af[mi], bf[ni], acc[mi][ni], 0, 0, 0);
  }

  float bcol[4];
#pragma unroll
  for (int ni = 0; ni < 4; ni++)
    bcol[ni] = bias[n0 + wc * 64 + ni * 16 + l15];
#pragma unroll
  for (int mi = 0; mi < 4; mi++)
#pragma unroll
    for (int ni = 0; ni < 4; ni++) {
      int col = n0 + wc * 64 + ni * 16 + l15;
      int row = m0 + wr * 64 + mi * 16 + quad * 4;
#pragma unroll
      for (int r = 0; r < 4; r++)
        out[(size_t)(row + r) * 768 + col] = acc[mi][ni][r] + bcol[ni];
    }
}

// ---------------------------------------------------------------------------
// launch
// ---------------------------------------------------------------------------
extern "C" void kernel_launch(void* const* d_in, const int* in_sizes, int n_in,
                              void* d_out, int out_size, void* d_ws, size_t ws_size,
                              hipStream_t stream) {
  const float* x      = (const float*)d_in[0];
  const float* w_qkv  = (const float*)d_in[1];
  const float* b_qkv  = (const float*)d_in[2];
  const float* w_proj = (const float*)d_in[3];
  const float* b_proj = (const float*)d_in[4];
  float* out = (float*)d_out;

  char* ws = (char*)d_ws;
  _Float16* wqkvT  = (_Float16*)(ws);
  _Float16* wprojT = (_Float16*)(ws + 3538944);
  _Float16* Qp     = (_Float16*)(ws + 4718592);
  _Float16* Kp     = (_Float16*)(ws + 29884416);
  _Float16* VTp    = (_Float16*)(ws + 55050240);
  _Float16* Ohp    = (_Float16*)(ws + 80216064);
  // total: 105381888 B (~100 MB)

  cvt_wt2_kernel<<<dim3(24, 96), 256, 0, stream>>>(w_qkv, wqkvT, w_proj, wprojT);
  gemm_qkv_kernel<<<dim3(2304), 256, 0, stream>>>(x, wqkvT, b_qkv, Qp, Kp, VTp);
  attn_kernel<<<dim3(768), 256, 0, stream>>>(Qp, Kp, VTp, Ohp);
  gemm_proj_kernel<<<dim3(768), 256, 0, stream>>>(Ohp, wprojT, b_proj, out);
}

// Round 9
// 299.516 us; speedup vs baseline: 1.5481x; 1.0098x over previous
//
#include <hip/hip_runtime.h>

// ---------------------------------------------------------------------------
// Fused MHA block on gfx950, fp16 MFMA pipeline.
//   qkv GEMM (16384x2304x768, A=fp32 fused-converted) -> per-head flash
//   attention (192 x 1024x1024x64) -> proj GEMM (16384x768x768)
// GEMMs: 128x256 tiles, 8 waves (2Mx4N), v_mfma_f32_16x16x32_f16,
//        r5's exact 2-phase loop per wave (same frags/acc/ds pattern),
//        linear LDS, double-buffered, 1 barrier/iter, XCD-swizzled grid.
//   vs r5/r8 128x128: staging/MFMA 256->187 B (A staged once per 256 cols),
//        ~16 waves/CU (2 blocks x 8) vs 12, half the blocks/epilogues.
//   Ledger: (256,{4,5}) regress; A-LDS-bypass regress (frag loads are
//        uncoalescable from global); 8-phase/T2/T5/T13 all null here.
//   qkv A: fp32 global -> regs -> RTN cvt -> ds_write (fused cvt_x).
//   qkv B + proj A,B: global_load_lds width-16 direct.
// Attention: v_mfma_f32_32x32x16_f16 transposed (S^T = K Q^T, O^T = V^T P^T),
//        P in registers (r1-measured-best).
// ---------------------------------------------------------------------------

typedef _Float16 half8 __attribute__((ext_vector_type(8)));
typedef _Float16 half4 __attribute__((ext_vector_type(4)));
typedef __fp16   fp16x2 __attribute__((ext_vector_type(2)));
typedef float    f32x4  __attribute__((ext_vector_type(4)));
typedef float    f32x16 __attribute__((ext_vector_type(16)));
typedef unsigned int u32x4 __attribute__((ext_vector_type(4)));

#define DI __device__ __forceinline__

constexpr int   BATCH  = 16;
constexpr int   SEQ    = 1024;
constexpr int   DM     = 768;
constexpr int   NH     = 12;
constexpr int   HD     = 64;
constexpr float SCALE  = 0.125f;          // 1/sqrt(64), folded into Q epilogue
constexpr float LOG2E  = 1.4426950408889634f;

DI void copy16(_Float16* dst, const _Float16* src) {
  *(u32x4*)dst = *(const u32x4*)src;
}

DI int pack_rtz(float a, float b) {
  union { fp16x2 h; int i; } u;
  u.h = __builtin_amdgcn_cvt_pkrtz(a, b);
  return u.i;
}

// async global->LDS, 16 B per lane; lds base must be wave-uniform,
// HW writes lane l at lds + l*16.
DI void gld16(const _Float16* g, _Float16* l) {
  __builtin_amdgcn_global_load_lds(
      (const __attribute__((address_space(1))) void*)g,
      (__attribute__((address_space(3))) void*)l, 16, 0, 0);
}

// ---------------------------------------------------------------------------
// converts (weights only; x conversion is fused into gemm_qkv)
// ---------------------------------------------------------------------------
// both weight transposes in one launch: wt[n*K+k] = w[k*N+n]
__global__ void cvt_wt2_kernel(const float* __restrict__ wq,
                               _Float16* __restrict__ wqT,
                               const float* __restrict__ wp,
                               _Float16* __restrict__ wpT) {
  __shared__ float tile[32][33];
  const int by = blockIdx.y;
  const float* w; _Float16* wt; int N, nb;
  if (by < 72) { w = wq; wt = wqT; N = 2304; nb = by * 32; }
  else         { w = wp; wt = wpT; N = 768;  nb = (by - 72) * 32; }
  const int K = 768;
  int kb = blockIdx.x * 32;
  int tx = threadIdx.x & 31, ty = threadIdx.x >> 5;   // ty 0..7
#pragma unroll
  for (int i = 0; i < 32; i += 8)
    tile[ty + i][tx] = w[(size_t)(kb + ty + i) * N + nb + tx];
  __syncthreads();
#pragma unroll
  for (int i = 0; i < 32; i += 8)
    wt[(size_t)(nb + ty + i) * K + kb + tx] = (_Float16)tile[tx][ty + i];
}

// ---------------------------------------------------------------------------
// GEMM1: qkv = x[16384x768 fp32] @ wqkvT^T + bias, scatter epilogue into
//   Q[bh][n][d] (prescaled by 0.125), K[bh][n][d], VT[bh][d][n]  (fp16)
// 128x256 tile, 512 thr (8 waves 2x4). A: fp32->regs->cvt->ds_write.
// B: global_load_lds. LDS/buf: As 4096 h + Bs 8192 h = 24 KB; 2 bufs.
// ---------------------------------------------------------------------------
__launch_bounds__(512, 3)
__global__ void gemm_qkv_kernel(const float* __restrict__ X,
                                const _Float16* __restrict__ Bt,
                                const float* __restrict__ bias,
                                _Float16* __restrict__ Qo,
                                _Float16* __restrict__ Ko,
                                _Float16* __restrict__ VTo) {
  __shared__ _Float16 sh[24576];       // 2 bufs x 12288 halves (49152 B)
  _Float16* Cs = sh;                   // epilogue alias (64*264 = 16896 halves)
  const int tid  = threadIdx.x;
  // XCD swizzle: all 9 column tiles of one m0 land on one XCD (lin&7)
  const int lin  = blockIdx.x;         // 1152 blocks, 1152%8==0 bijective
  const int xcd  = lin & 7, j = lin >> 3;
  const int ct   = j % 9;              // 0..8 col tiles of 256
  const int m0   = ((j / 9) * 8 + xcd) * 128;
  const int n0   = ct * 256;
  const int w    = tid >> 6, lane = tid & 63;
  const int quad = lane >> 4, l15 = lane & 15;
  const int wr   = w >> 2, wc = w & 3; // 2 row-waves x 4 col-waves

  f32x4 acc[4][4] = {};

  // ---- A staging geometry (512 thr, one granule each): row tid>>2, seg tid&3
  const int rA = tid >> 2, sA = tid & 3;
  const float* gaA = X + (size_t)(m0 + rA) * 768 + sA * 8;
  const int so = rA * 32 + sA * 8;     // linear [128][32] dest (halves)

  // ---- B staging (gld_lds): granule g = w*128 + c*64 + lane (c = call 0/1)
  //      row g>>2 (0..255), seg g&3; dest = g*8 halves.
  const _Float16* gbB = Bt + (size_t)(n0 + ((w * 128 + lane) >> 2)) * 768
                           + (lane & 3) * 8;
  const int ldst = w * 1024;           // B dest halves, call 0 (call 1: +512)

  auto CVT_WRITE = [&](float4 a0, float4 a1, _Float16* As) {
    half8 h0;
    h0[0] = (_Float16)a0.x; h0[1] = (_Float16)a0.y;
    h0[2] = (_Float16)a0.z; h0[3] = (_Float16)a0.w;
    h0[4] = (_Float16)a1.x; h0[5] = (_Float16)a1.y;
    h0[6] = (_Float16)a1.z; h0[7] = (_Float16)a1.w;
    *(half8*)(As + so) = h0;
  };

  // prologue: tile 0 -> buf 0  (As at 0, Bs at 4096)
  {
    float4 a0 = *(const float4*)(gaA);
    float4 a1 = *(const float4*)(gaA + 4);
    CVT_WRITE(a0, a1, sh);
    gld16(gbB,            sh + 4096 + ldst);
    gld16(gbB + 16 * 768, sh + 4096 + ldst + 512);
  }

  for (int kt = 0; kt < 24; ++kt) {
    __syncthreads();                   // drains vm (B) + lgkm (A writes)
    float4 a0, a1;
    if (kt < 23) {                     // prefetch next tile
      const int k0 = (kt + 1) * 32;
      a0 = *(const float4*)(gaA + k0);
      a1 = *(const float4*)(gaA + k0 + 4);
      _Float16* Bsn = sh + ((kt + 1) & 1) * 12288 + 4096;
      gld16(gbB + k0,            Bsn + ldst);
      gld16(gbB + k0 + 16 * 768, Bsn + ldst + 512);
    }

    const _Float16* As = sh + (kt & 1) * 12288;
    const _Float16* Bs = As + 4096;

    half8 af[4], bf[4];
#pragma unroll
    for (int mi = 0; mi < 4; mi++)
      af[mi] = *(const half8*)&As[(wr * 64 + mi * 16 + l15) * 32 + quad * 8];
#pragma unroll
    for (int ni = 0; ni < 4; ni++)
      bf[ni] = *(const half8*)&Bs[(wc * 64 + ni * 16 + l15) * 32 + quad * 8];
#pragma unroll
    for (int mi = 0; mi < 4; mi++)
#pragma unroll
      for (int ni = 0; ni < 4; ni++)
        acc[mi][ni] = __builtin_amdgcn_mfma_f32_16x16x32_f16(
            af[mi], bf[ni], acc[mi][ni], 0, 0, 0);

    if (kt < 23)                       // stage converted A into other buf
      CVT_WRITE(a0, a1, sh + ((kt + 1) & 1) * 12288);
  }
  __syncthreads();

  const int   sec    = ct / 3;         // 0=Q 1=K 2=V
  const int   h0     = (ct % 3) * 4;   // 4 heads per 256-col tile
  const float oscale = (sec == 0) ? SCALE : 1.0f;
  float bcol[4];
#pragma unroll
  for (int ni = 0; ni < 4; ni++)
    bcol[ni] = bias[n0 + wc * 64 + ni * 16 + l15];

  const int b     = m0 >> 10;
  const int nrow0 = m0 & 1023;

  // two passes of 64 rows each through Cs[64][264]
#pragma unroll
  for (int p = 0; p < 2; ++p) {
    if (p) __syncthreads();            // pass-0 reads done before overwrite
    if (wr == p) {
#pragma unroll
      for (int mi = 0; mi < 4; mi++)
#pragma unroll
        for (int ni = 0; ni < 4; ni++) {
          int col = wc * 64 + ni * 16 + l15;
          int row = mi * 16 + quad * 4;
#pragma unroll
          for (int r = 0; r < 4; r++)
            Cs[(row + r) * 264 + col] =
                (_Float16)((acc[mi][ni][r] + bcol[ni]) * oscale);
        }
    }
    __syncthreads();

    if (sec < 2) {
      _Float16* dst = (sec == 0) ? Qo : Ko;
      int row = tid >> 3, seg = tid & 7;     // 64 rows x 8 segs of 32
      int hl = seg >> 1, off32 = (seg & 1) * 32;
      _Float16* g = dst +
          ((size_t)((b * NH + h0 + hl) * SEQ + nrow0 + p * 64 + row)) * HD + off32;
      const _Float16* s = &Cs[row * 264 + hl * 64 + off32];
      copy16(g, s);
      copy16(g + 8, s + 8);
      copy16(g + 16, s + 16);
      copy16(g + 24, s + 24);
    } else {
      int c = tid & 255, rh = tid >> 8;      // col, row half (32 rows each)
      int hl = c >> 6, d = c & 63;
      _Float16 tmp[32];
#pragma unroll
      for (int jj = 0; jj < 32; jj++) tmp[jj] = Cs[(rh * 32 + jj) * 264 + c];
      _Float16* g = VTo + ((size_t)((b * NH + h0 + hl) * HD + d)) * SEQ
                        + nrow0 + p * 64 + rh * 32;
#pragma unroll
      for (int jj = 0; jj < 4; jj++)
        copy16(g + jj * 8, (const _Float16*)&tmp[jj * 8]);
    }
  }
}

// ---------------------------------------------------------------------------
// Flash attention, transposed: one wg = (bh, 256-q tile), 4 waves x 64 q.
// S^T = K Q^T (32x32x16 MFMA), P^T kept in registers via half-swap shuffles,
// O^T = V^T P^T.  K-tile 64, double-buffered LDS staging.
// ---------------------------------------------------------------------------
__launch_bounds__(256, 2)
__global__ void attn_kernel(const _Float16* __restrict__ Q,
                            const _Float16* __restrict__ K,
                            const _Float16* __restrict__ VT,
                            _Float16* __restrict__ Oh) {
  __shared__ _Float16 smem[2][2][64 * 72];   // [buf][K/V][64 rows][72]
  _Float16* OLds = &smem[0][0][0];           // aliased epilogue staging (36864B)

  const int tid = threadIdx.x;
  const int i   = blockIdx.x;
  const int bh  = (i & 7) * 24 + ((i >> 3) >> 2);   // XCD swizzle: 4 q-blocks
  const int q0  = ((i >> 3) & 3) * 256;             //  of one bh share an XCD
  const int b   = bh / NH, hh = bh - b * NH;
  const int w   = tid >> 6, lane = tid & 63;
  const int l31 = lane & 31, h = lane >> 5;

  const _Float16* Qg = Q  + (size_t)bh * SEQ * HD;
  const _Float16* Kg = K  + (size_t)bh * SEQ * HD;
  const _Float16* Vg = VT + (size_t)bh * HD * SEQ;

  // persistent Q B-frags: qb[N][s] ; B[k=d][n=q] read from Q[q][d] row-major
  half8 qb[2][4];
#pragma unroll
  for (int N = 0; N < 2; N++) {
    const _Float16* qrow = Qg + (size_t)(q0 + w * 64 + N * 32 + l31) * HD + h * 8;
#pragma unroll
    for (int s = 0; s < 4; s++)
      qb[N][s] = *(const half8*)(qrow + s * 16);
  }

  // staging: threads 0-127 stage K tile, 128-255 stage V^T tile (64B each)
  const int  sr  = (tid & 127) >> 1;
  const int  sp  = tid & 1;
  const bool isK = tid < 128;
  const _Float16* sg = isK ? (Kg + sr * HD + sp * 32)
                           : (Vg + (size_t)sr * SEQ + sp * 32);
  const int sstep = isK ? 64 * HD : 64;
  const int soff  = (isK ? 0 : 64 * 72) + sr * 72 + sp * 32;

  u32x4 pf[4];
#pragma unroll
  for (int c = 0; c < 4; c++) pf[c] = *(const u32x4*)(sg + c * 8);
#pragma unroll
  for (int c = 0; c < 4; c++) *(u32x4*)(&smem[0][0][0] + soff + c * 8) = pf[c];

  f32x16 of[2][2];
#pragma unroll
  for (int D = 0; D < 2; D++)
#pragma unroll
    for (int N = 0; N < 2; N++)
#pragma unroll
      for (int r = 0; r < 16; r++) of[D][N][r] = 0.f;
  float m_[2] = {-1e30f, -1e30f}, l_[2] = {0.f, 0.f};

  for (int kt = 0; kt < 16; ++kt) {
    if (kt < 15) {
      const _Float16* nsg = sg + (kt + 1) * sstep;
#pragma unroll
      for (int c = 0; c < 4; c++) pf[c] = *(const u32x4*)(nsg + c * 8);
    }
    __syncthreads();
    const _Float16* Ks = &smem[kt & 1][0][0];
    const _Float16* Vs = &smem[kt & 1][1][0];

    // S^T = K Q^T : 2 m-frags (64 keys) x 2 n-frags (64 q)
    f32x16 sf[2][2];
#pragma unroll
    for (int M = 0; M < 2; M++)
#pragma unroll
      for (int N = 0; N < 2; N++)
#pragma unroll
        for (int r = 0; r < 16; r++) sf[M][N][r] = 0.f;
#pragma unroll
    for (int s = 0; s < 4; s++) {
      half8 ka0 = *(const half8*)&Ks[l31 * 72 + s * 16 + h * 8];
      half8 ka1 = *(const half8*)&Ks[(32 + l31) * 72 + s * 16 + h * 8];
#pragma unroll
      for (int N = 0; N < 2; N++) {
        sf[0][N] = __builtin_amdgcn_mfma_f32_32x32x16_f16(ka0, qb[N][s], sf[0][N], 0, 0, 0);
        sf[1][N] = __builtin_amdgcn_mfma_f32_32x32x16_f16(ka1, qb[N][s], sf[1][N], 0, 0, 0);
      }
    }

    // online softmax; stats are per q = per lane (col of S^T)
    float alpha[2], c1[2], tsum[2];
#pragma unroll
    for (int N = 0; N < 2; N++) {
      float tmax = -1e30f;
#pragma unroll
      for (int r = 0; r < 16; r++)
        tmax = fmaxf(tmax, fmaxf(sf[0][N][r], sf[1][N][r]));
      tmax = fmaxf(tmax, __shfl_xor(tmax, 32, 64));
      float mnew = fmaxf(m_[N], tmax);
      alpha[N] = __builtin_amdgcn_exp2f((m_[N] - mnew) * LOG2E);
      m_[N] = mnew;
      c1[N] = mnew * LOG2E;
      tsum[N] = 0.f;
    }

    // exp -> P^T, pack fp16 pairs into dwords (kept in registers)
    int pdw[2][2][8];
#pragma unroll
    for (int M = 0; M < 2; M++)
#pragma unroll
      for (int N = 0; N < 2; N++) {
#pragma unroll
        for (int r = 0; r < 16; r++) {
          float p = __builtin_amdgcn_exp2f(sf[M][N][r] * LOG2E - c1[N]);
          sf[M][N][r] = p;
          tsum[N] += p;
        }
#pragma unroll
        for (int u = 0; u < 8; u++)
          pdw[M][N][u] = pack_rtz(sf[M][N][2 * u], sf[M][N][2 * u + 1]);
      }
#pragma unroll
    for (int N = 0; N < 2; N++) {
      tsum[N] += __shfl_xor(tsum[N], 32, 64);
      l_[N] = l_[N] * alpha[N] + tsum[N];
    }
#pragma unroll
    for (int D = 0; D < 2; D++)
#pragma unroll
      for (int N = 0; N < 2; N++)
#pragma unroll
        for (int r = 0; r < 16; r++) of[D][N][r] *= alpha[N];

    // O^T += V^T P^T ; P^T B-frags assembled from pdw via lane^32 half-swap
#pragma unroll
    for (int t = 0; t < 4; ++t) {
      const int M = t >> 1, s2 = (t & 1) * 4;
      half8 va0 = *(const half8*)&Vs[l31 * 72 + t * 16 + h * 8];
      half8 va1 = *(const half8*)&Vs[(32 + l31) * 72 + t * 16 + h * 8];
#pragma unroll
      for (int N = 0; N < 2; N++) {
        int a0 = pdw[M][N][s2 + 0], a1 = pdw[M][N][s2 + 1];
        int a2 = pdw[M][N][s2 + 2], a3 = pdw[M][N][s2 + 3];
        int e0 = h ? a0 : a2, e1 = h ? a1 : a3;
        int r0 = __shfl_xor(e0, 32, 64), r1 = __shfl_xor(e1, 32, 64);
        union { u32x4 u; half8 hv; } bb;
        bb.u[0] = h ? r0 : a0; bb.u[1] = h ? r1 : a1;
        bb.u[2] = h ? a2 : r0; bb.u[3] = h ? a3 : r1;
        of[0][N] = __builtin_amdgcn_mfma_f32_32x32x16_f16(va0, bb.hv, of[0][N], 0, 0, 0);
        of[1][N] = __builtin_amdgcn_mfma_f32_32x32x16_f16(va1, bb.hv, of[1][N], 0, 0, 0);
      }
    }

    if (kt < 15) {
      _Float16* dst = &smem[(kt + 1) & 1][0][0] + soff;
#pragma unroll
      for (int c = 0; c < 4; c++) *(u32x4*)(dst + c * 8) = pf[c];
    }
  }

  // epilogue: normalize, transpose O^T -> O through LDS, coalesced store
  __syncthreads();                       // all waves done with staging buffers
  float inv[2] = {1.0f / l_[0], 1.0f / l_[1]};
  int* OW = (int*)OLds;
#pragma unroll
  for (int N = 0; N < 2; N++) {
    const int q_local = w * 64 + N * 32 + l31;
#pragma unroll
    for (int D = 0; D < 2; D++)
#pragma unroll
      for (int u = 0; u < 8; u++) {
        int v = pack_rtz(of[D][N][2 * u] * inv[N], of[D][N][2 * u + 1] * inv[N]);
        int dwi = 16 * D + 4 * (u >> 1) + (u & 1) + 2 * h;
        OW[q_local * 36 + dwi] = v;
      }
  }
  __syncthreads();
#pragma unroll
  for (int p = 0; p < 8; p++) {
    int q = p * 32 + (tid >> 3), c = tid & 7;
    *(u32x4*)(Oh + (size_t)(b * SEQ + q0 + q) * DM + hh * HD + c * 8) =
        *(const u32x4*)&OLds[q * 72 + c * 8];
  }
}

// ---------------------------------------------------------------------------
// GEMM2: out = Oh[16384x768] @ wprojT^T + bias  (fp32 direct stores)
// 128x256 tile, 512 thr. A,B via global_load_lds; same 2-phase loop.
// ---------------------------------------------------------------------------
__launch_bounds__(512, 3)
__global__ void gemm_proj_kernel(const _Float16* __restrict__ A,
                                 const _Float16* __restrict__ Bt,
                                 const float* __restrict__ bias,
                                 float* __restrict__ out) {
  __shared__ _Float16 sh[24576];       // 2 bufs x (As 4096 + Bs 8192)
  const int tid  = threadIdx.x;
  // XCD swizzle: all 3 column tiles of one m0 on one XCD
  const int lin  = blockIdx.x;         // 384 blocks, 384%8==0 bijective
  const int xcd  = lin & 7, j = lin >> 3;
  const int ct   = j % 3;
  const int m0   = ((j / 3) * 8 + xcd) * 128;
  const int n0   = ct * 256;
  const int w    = tid >> 6, lane = tid & 63;
  const int quad = lane >> 4, l15 = lane & 15;
  const int wr   = w >> 2, wc = w & 3;

  f32x4 acc[4][4] = {};

  // A: granule g = w*64 + lane (512 granules) -> row g>>2, seg g&3
  const _Float16* gaA = A + (size_t)(m0 + ((w * 64 + lane) >> 2)) * 768
                          + (lane & 3) * 8;
  const int ldstA = w * 512;
  // B: granule g = w*128 + c*64 + lane -> row g>>2 (0..255), seg g&3
  const _Float16* gbB = Bt + (size_t)(n0 + ((w * 128 + lane) >> 2)) * 768
                           + (lane & 3) * 8;
  const int ldstB = w * 1024;

  auto STAGE = [&](int buf, int kt) {
    _Float16* As = sh + buf * 12288;
    _Float16* Bs = As + 4096;
    const _Float16* a = gaA + kt * 32;
    const _Float16* b = gbB + kt * 32;
    gld16(a,            As + ldstA);
    gld16(b,            Bs + ldstB);
    gld16(b + 16 * 768, Bs + ldstB + 512);
  };

  STAGE(0, 0);

  for (int kt = 0; kt < 24; ++kt) {
    __syncthreads();
    if (kt < 23) STAGE((kt + 1) & 1, kt + 1);

    const _Float16* As = sh + (kt & 1) * 12288;
    const _Float16* Bs = As + 4096;

    half8 af[4], bf[4];
#pragma unroll
    for (int mi = 0; mi < 4; mi++)
      af[mi] = *(const half8*)&As[(wr * 64 + mi * 16 + l15) * 32 + quad * 8];
#pragma unroll
    for (int ni = 0; ni < 4; ni++)
      bf[ni] = *(const half8*)&Bs[(wc * 64 + ni * 16 + l15) * 32 + quad * 8];
#pragma unroll
    for (int mi = 0; mi < 4; mi++)
#pragma unroll
      for (int ni = 0; ni < 4; ni++)
        acc[mi][ni] = __builtin_amdgcn_mfma_f32_16x16x32_f16(
            af[mi], bf[ni], acc[mi][ni], 0, 0, 0);
  }

  float bcol[4];
#pragma unroll
  for (int ni = 0; ni < 4; ni++)
    bcol[ni] = bias[n0 + wc * 64 + ni * 16 + l15];
#pragma unroll
  for (int mi = 0; mi < 4; mi++)
#pragma unroll
    for (int ni = 0; ni < 4; ni++) {
      int col = n0 + wc * 64 + ni * 16 + l15;
      int row = m0 + wr * 64 + mi * 16 + quad * 4;
#pragma unroll
      for (int r = 0; r < 4; r++)
        out[(size_t)(row + r) * 768 + col] = acc[mi][ni][r] + bcol[ni];
    }
}

// ---------------------------------------------------------------------------
// launch
// ---------------------------------------------------------------------------
extern "C" void kernel_launch(void* const* d_in, const int* in_sizes, int n_in,
                              void* d_out, int out_size, void* d_ws, size_t ws_size,
                              hipStream_t stream) {
  const float* x      = (const float*)d_in[0];
  const float* w_qkv  = (const float*)d_in[1];
  const float* b_qkv  = (const float*)d_in[2];
  const float* w_proj = (const float*)d_in[3];
  const float* b_proj = (const float*)d_in[4];
  float* out = (float*)d_out;

  char* ws = (char*)d_ws;
  _Float16* wqkvT  = (_Float16*)(ws);
  _Float16* wprojT = (_Float16*)(ws + 3538944);
  _Float16* Qp     = (_Float16*)(ws + 4718592);
  _Float16* Kp     = (_Float16*)(ws + 29884416);
  _Float16* VTp    = (_Float16*)(ws + 55050240);
  _Float16* Ohp    = (_Float16*)(ws + 80216064);
  // total: 105381888 B (~100 MB)

  cvt_wt2_kernel<<<dim3(24, 96), 256, 0, stream>>>(w_qkv, wqkvT, w_proj, wprojT);
  gemm_qkv_kernel<<<dim3(1152), 512, 0, stream>>>(x, wqkvT, b_qkv, Qp, Kp, VTp);
  attn_kernel<<<dim3(768), 256, 0, stream>>>(Qp, Kp, VTp, Ohp);
  gemm_proj_kernel<<<dim3(384), 512, 0, stream>>>(Ohp, wprojT, b_proj, out);
}